// Round 5
// baseline (1646.024 us; speedup 1.0000x reference)
//
#include <hip/hip_runtime.h>
#include <math.h>

#define NBATCH 262144
#define INVSQH 0.08838834764831845f   // 1/sqrt(128)

typedef float f32x4 __attribute__((ext_vector_type(4)));
typedef short s16x8 __attribute__((ext_vector_type(8)));
typedef __bf16 bf16x2_t __attribute__((ext_vector_type(2)));

// ---- workspace layout (bytes) ----
// Wres bf16, fragment-major: 64 stages * 32768 B.
//   bf16 index = sidx*16384 + ((o>>4)*4 + (k>>5))*512 + (((k>>3)&3)*16 + (o&15))*8 + (k&7)
#define WSR_OFF 0
#define WSF_OFF 2097152           // Wf padded [32][128]: 16 * 8192 B, same fragment-major form
#define WS0_OFF 2228224           // W0 col0 packed: 16*128 f32
#define WSB_OFF 2236416           // proj bias padded: 16*32 f32
#define REC_OFF 2238464           // 16 * 40 f32 (cw9 ch9 d9 lu4 lub2)
#define LDC_OFF 2241024           // 1 f32: sum log-diag

#define P1S 36                    // p1 row stride in floats (odd-ish phase for banks)

__device__ __forceinline__ float softplusf(float x) {
    return (x > 15.f) ? x : log1pf(__expf(x));
}
__device__ __forceinline__ unsigned short f2bf(float x) {
    unsigned u = __float_as_uint(x);
    unsigned r = (u + 0x7FFFu + ((u >> 16) & 1u)) >> 16;   // RNE
    return (unsigned short)r;
}
__device__ __forceinline__ unsigned pack2bf(float a, float b) {
#if __has_builtin(__builtin_amdgcn_cvt_pk_bf16_f32)
    bf16x2_t r = __builtin_amdgcn_cvt_pk_bf16_f32(a, b);
    return __builtin_bit_cast(unsigned, r);
#else
    return (unsigned)f2bf(a) | ((unsigned)f2bf(b) << 16);
#endif
}

__device__ __forceinline__ void rqs_solve(float y, float yc, float yk, float hk, float xk,
                                          float wk, float dk, float dk1,
                                          float& xout, float& ldout)
{
    float sk = hk / wk;
    float dy = yc - yk;
    float t2 = dk + dk1 - 2.f * sk;
    float av = dy * t2 + hk * (sk - dk);
    float bv = hk * dk - dy * t2;
    float cv = -sk * dy;
    float disc = fmaxf(bv * bv - 4.f * av * cv, 0.f);
    float theta = 2.f * cv / (-bv - sqrtf(disc));
    float xo = fmaf(theta, wk, xk);
    float om = 1.f - theta;
    float denom = fmaf(t2, theta * om, sk);
    float dnum = sk * sk * (dk1 * theta * theta + 2.f * sk * theta * om + dk * om * om);
    float ldf = __logf(dnum) - 2.f * __logf(denom);
    bool inside = (y >= -3.f) && (y <= 3.f);
    xout  = inside ? xo : y;
    ldout = inside ? -ldf : 0.f;
}

// full RQS inverse from raw params p[0..22] (dim-1, per-sample)
__device__ __forceinline__ void rqs_inv(float y, const float* __restrict__ p,
                                        float& xout, float& ldout)
{
    float uw[8], uh[8];
#pragma unroll
    for (int j = 0; j < 8; ++j) uw[j] = p[j] * INVSQH;
#pragma unroll
    for (int j = 0; j < 8; ++j) uh[j] = p[8 + j] * INVSQH;
    float mw = uw[0], mh = uh[0];
#pragma unroll
    for (int j = 1; j < 8; ++j) { mw = fmaxf(mw, uw[j]); mh = fmaxf(mh, uh[j]); }
    float ew[8], eh[8], sw = 0.f, sh = 0.f;
#pragma unroll
    for (int j = 0; j < 8; ++j) {
        ew[j] = __expf(uw[j] - mw); sw += ew[j];
        eh[j] = __expf(uh[j] - mh); sh += eh[j];
    }
    float isw = 0.992f / sw, ish = 0.992f / sh;
    float cw[9], ch[9];
    cw[0] = -3.f; ch[0] = -3.f;
    float aw = 0.f, ah = 0.f;
#pragma unroll
    for (int j = 0; j < 8; ++j) {
        aw += 0.001f + ew[j] * isw;
        ah += 0.001f + eh[j] * ish;
        cw[j + 1] = 6.f * aw - 3.f;
        ch[j + 1] = 6.f * ah - 3.f;
    }
    cw[8] = 3.f; ch[8] = 3.f;
    float d[9];
    d[0] = 1.f; d[8] = 1.f;
#pragma unroll
    for (int j = 0; j < 7; ++j) d[j + 1] = 0.001f + softplusf(p[16 + j]);

    float yc = fminf(fmaxf(y, -3.f), 3.f);
    float yk = ch[0], hk = ch[1] - ch[0], xk = cw[0], wk = cw[1] - cw[0];
    float dk = d[0], dk1 = d[1];
#pragma unroll
    for (int j = 1; j < 8; ++j) {
        bool cge = (yc >= ch[j]);
        yk  = cge ? ch[j] : yk;
        hk  = cge ? (ch[j + 1] - ch[j]) : hk;
        xk  = cge ? cw[j] : xk;
        wk  = cge ? (cw[j + 1] - cw[j]) : wk;
        dk  = cge ? d[j] : dk;
        dk1 = cge ? d[j + 1] : dk1;
    }
    rqs_solve(y, yc, yk, hk, xk, wk, dk, dk1, xout, ldout);
}

// RQS inverse from precomputed knots rec = {cw[9], ch[9], d[9]} (dim-0, per-layer const)
__device__ __forceinline__ void rqs_knots(float y, const float* __restrict__ rec,
                                          float& xout, float& ldout)
{
    const float* cw = rec;
    const float* ch = rec + 9;
    const float* dd = rec + 18;
    float yc = fminf(fmaxf(y, -3.f), 3.f);
    float yk = ch[0], hk = ch[1] - ch[0], xk = cw[0], wk = cw[1] - cw[0];
    float dk = dd[0], dk1 = dd[1];
#pragma unroll
    for (int j = 1; j < 8; ++j) {
        bool cge = (yc >= ch[j]);
        yk  = cge ? ch[j] : yk;
        hk  = cge ? (ch[j + 1] - ch[j]) : hk;
        xk  = cge ? cw[j] : xk;
        wk  = cge ? (cw[j + 1] - cw[j]) : wk;
        dk  = cge ? dd[j] : dk;
        dk1 = cge ? dd[j + 1] : dk1;
    }
    rqs_solve(y, yc, yk, hk, xk, wk, dk, dk1, xout, ldout);
}

// load one 8-fragment W group (global, coalesced 1 KB per fragment)
__device__ __forceinline__ void load_group(s16x8 dst[8], const char* base, int stride, int lane)
{
#pragma unroll
    for (int i = 0; i < 8; ++i)
        dst[i] = *(const s16x8*)(base + i * stride + (lane << 4));
}

// packed bf16x4 store of one D-frag into the wave-private A region.
// element (m_local, k) at byte m_local*256 + ((k>>3)^(m&7))*16 + (k&7)*2.
// lane (q,tx) holds k = nt*16 + 4q + {0..3} for m_local = mt*16 + tx.
__device__ __forceinline__ void storeA(char* A, int mt, int tx, int q, int tx7, int nt, f32x4 v)
{
    unsigned d0 = pack2bf(v[0], v[1]);
    unsigned d1 = pack2bf(v[2], v[3]);
    int row = mt * 16 + tx;
    int chunk = ((nt << 1) + (q >> 1)) ^ tx7;
    *(uint2*)(A + (row << 8) + (chunk << 4) + ((q & 1) << 3)) = make_uint2(d0, d1);
}

// read one B-frag (act) for k-step ks, m-tile mt from the wave-private A region
__device__ __forceinline__ s16x8 readB(const char* A, int mt, int tx, int q, int tx7, int ks)
{
    int row = mt * 16 + tx;
    int chunk = ((ks << 2) + q) ^ tx7;
    return *(const s16x8*)(A + (row << 8) + (chunk << 4));
}

// One 32m x 128n x 128k stage, fully wave-private (no barriers).
// acc[nt][mt]; W A-frags stream from global with 1-group-deep pipeline:
// entry invariant: wfA holds this stage's ks0 group; exit: wfA holds nxt_base's group.
template <int BSTAGE, int RELUOUT>
__device__ __forceinline__ void res_stage(char* A, const char* own_base,
                                          const char* nxt_base, int nxt_stride,
                                          const float* biasrow,
                                          f32x4 h[8][2], s16x8 wfA[8], s16x8 wfB[8],
                                          int q, int tx, int lane)
{
    const int tx7 = tx & 7;
    f32x4 acc[8][2];
#pragma unroll
    for (int nt = 0; nt < 8; ++nt) {
        float4 bv = *(const float4*)(biasrow + nt * 16 + (q << 2));
        f32x4 b; b[0] = bv.x; b[1] = bv.y; b[2] = bv.z; b[3] = bv.w;
#pragma unroll
        for (int mt = 0; mt < 2; ++mt)
            acc[nt][mt] = BSTAGE ? (h[nt][mt] + b) : b;
    }

#pragma unroll
    for (int ks = 0; ks < 4; ++ks) {
        s16x8* cur = (ks & 1) ? wfB : wfA;
        s16x8* nxt = (ks & 1) ? wfA : wfB;
        const char* nb = (ks < 3) ? (own_base + (ks + 1) * 1024) : nxt_base;
        int str = (ks < 3) ? 4096 : nxt_stride;
        load_group(nxt, nb, str, lane);
        s16x8 bf[2];
#pragma unroll
        for (int mt = 0; mt < 2; ++mt)
            bf[mt] = readB(A, mt, tx, q, tx7, ks);
#pragma unroll
        for (int nt = 0; nt < 8; ++nt)
#pragma unroll
            for (int mt = 0; mt < 2; ++mt)
                acc[nt][mt] = __builtin_amdgcn_mfma_f32_16x16x32_bf16(cur[nt], bf[mt], acc[nt][mt], 0, 0, 0);
    }

#pragma unroll
    for (int nt = 0; nt < 8; ++nt)
#pragma unroll
        for (int mt = 0; mt < 2; ++mt) {
            if (BSTAGE) h[nt][mt] = acc[nt][mt];
            f32x4 v = acc[nt][mt];
            if (RELUOUT) {
                v[0] = fmaxf(v[0], 0.f); v[1] = fmaxf(v[1], 0.f);
                v[2] = fmaxf(v[2], 0.f); v[3] = fmaxf(v[3], 0.f);
            }
            storeA(A, mt, tx, q, tx7, nt, v);
        }
}

// ---------------- prep kernel (identical layout to R4, correctness-proven) ----------------
extern "C" __global__ void nsf_prep(const float* __restrict__ Wresg, const float* __restrict__ Wfg,
                                    const float* __restrict__ bfg, const float* __restrict__ W0g,
                                    const float* __restrict__ lulg, const float* __restrict__ luug,
                                    const float* __restrict__ ludg, const float* __restrict__ lubg,
                                    const int* __restrict__ permsg, char* __restrict__ ws)
{
    int t = blockIdx.x * blockDim.x + threadIdx.x;
    int stride = gridDim.x * blockDim.x;
    unsigned short* wr = (unsigned short*)(ws + WSR_OFF);
    unsigned short* wf = (unsigned short*)(ws + WSF_OFF);
    float* ws0 = (float*)(ws + WS0_OFF);
    float* wsb = (float*)(ws + WSB_OFF);

    for (int e = t; e < 16 * 4 * 16384; e += stride) {
        int sidx = e >> 14;
        int rem = e & 16383;
        int o = rem >> 7, k = rem & 127;
        wr[sidx * 16384 + ((o >> 4) * 4 + (k >> 5)) * 512
           + (((k >> 3) & 3) * 16 + (o & 15)) * 8 + (k & 7)] = f2bf(Wresg[e]);
    }
    for (int e = t; e < 16 * 32 * 128; e += stride) {
        int L = e >> 12;
        int rem = e & 4095;
        int o = rem >> 7, k = rem & 127;
        float x = (o < 23) ? Wfg[(L * 46 + 23 + o) * 128 + k] : 0.f;
        wf[L * 4096 + ((o >> 4) * 4 + (k >> 5)) * 512
           + (((k >> 3) & 3) * 16 + (o & 15)) * 8 + (k & 7)] = f2bf(x);
    }
    for (int e = t; e < 16 * 128; e += stride)
        ws0[e] = W0g[2 * e];
    for (int e = t; e < 16 * 32; e += stride) {
        int L = e >> 5, o = e & 31;
        wsb[e] = (o < 23) ? bfg[L * 46 + 23 + o] : 0.f;
    }
    if (t < 16) {
        int L = t;
        float* rec = (float*)(ws + REC_OFF) + L * 40;
        const float* p = bfg + L * 46;
        for (int half = 0; half < 2; ++half) {
            float u[8], m = -1e30f;
            for (int j = 0; j < 8; ++j) { u[j] = p[half * 8 + j] * INVSQH; m = fmaxf(m, u[j]); }
            float e[8], s = 0.f;
            for (int j = 0; j < 8; ++j) { e[j] = expf(u[j] - m); s += e[j]; }
            float cum = 0.f;
            rec[half * 9 + 0] = -3.f;
            for (int j = 0; j < 8; ++j) {
                cum += 0.001f + 0.992f * e[j] / s;
                rec[half * 9 + 1 + j] = 6.f * cum - 3.f;
            }
            rec[half * 9 + 8] = 3.f;
        }
        rec[18] = 1.f; rec[26] = 1.f;
        for (int j = 0; j < 7; ++j) {
            float x = p[16 + j];
            rec[19 + j] = 0.001f + ((x > 15.f) ? x : log1pf(expf(x)));
        }
        float x0 = ludg[2 * L], x1 = ludg[2 * L + 1];
        float dg0 = 0.001f + ((x0 > 15.f) ? x0 : log1pf(expf(x0)));
        float dg1 = 0.001f + ((x1 > 15.f) ? x1 : log1pf(expf(x1)));
        float ll = lulg[L], uu = luug[L];
        float det = dg0 * dg1;
        float c00 = (ll * uu + dg1) / det, c01 = -uu / det;
        float c10 = -ll / dg1, c11 = 1.f / dg1;
        int pa = permsg[2 * L], pb = permsg[2 * L + 1];
        rec[27] = pa ? c10 : c00; rec[28] = pa ? c11 : c01;
        rec[29] = pb ? c10 : c00; rec[30] = pb ? c11 : c01;
        rec[31] = lubg[2 * L];    rec[32] = lubg[2 * L + 1];
    }
    if (t == 16) {
        float s = 0.f;
        for (int L = 0; L < 16; ++L) {
            float x0 = ludg[2 * L], x1 = ludg[2 * L + 1];
            float dg0 = 0.001f + ((x0 > 15.f) ? x0 : log1pf(expf(x0)));
            float dg1 = 0.001f + ((x1 > 15.f) ? x1 : log1pf(expf(x1)));
            s += logf(dg0) + logf(dg1);
        }
        *(float*)(ws + LDC_OFF) = s;
    }
}

// ---------------- main fused kernel: zero barriers, wave-private tiles ----------------
extern "C" __global__ __launch_bounds__(256, 2)
void nsf_kernel(const float* __restrict__ z0g, const float* __restrict__ xg,
                const float* __restrict__ sgg,
                const float* __restrict__ n1w1, const float* __restrict__ n1b1,
                const float* __restrict__ n1w2, const float* __restrict__ n1b2,
                const float* __restrict__ n2w1, const float* __restrict__ n2b1,
                const float* __restrict__ n2w2, const float* __restrict__ n2b2,
                const float* __restrict__ b0g,  const float* __restrict__ bresg,
                const char* __restrict__ ws, float* __restrict__ outg)
{
    __shared__ char  Abuf[4][32 * 256];     // per-wave act region (bf16, swizzled chunks)
    __shared__ float p1f[4][32 * P1S];      // per-wave spline params
    __shared__ float o0sh[4][32];           // per-wave out0

    const int tid = threadIdx.x;
    const int lane = tid & 63, w = tid >> 6;
    const int q = lane >> 4, tx = lane & 15, tx7 = tx & 7;
    const int ml = lane & 31;               // owned sample (lanes 32..63 duplicate 0..31)
    char*  A   = Abuf[w];
    float* p1w = p1f[w];
    float* o0w = o0sh[w];
    const int sbase = blockIdx.x * 128 + w * 32;

    const char* wsW = ws + WSR_OFF;
    const char* wsF = ws + WSF_OFF;
    const float* ws0 = (const float*)(ws + WS0_OFF);
    const float* wsb = (const float*)(ws + WSB_OFF);
    const float* recs = (const float*)(ws + REC_OFF);

    s16x8 wfA[8], wfB[8];
    load_group(wfA, wsW, 4096, lane);       // L0 stage0 ks0 group, in flight over the MLP

    // ---- conditioning MLPs (per owned sample, duplicated on the upper half-wave) ----
    float zz0, zz1, ld = 0.f;
    {
        int s = sbase + ml;
        float za = z0g[2 * s], zb = z0g[2 * s + 1];
        float xa = xg[2 * s],  xb = xg[2 * s + 1];
        float sg = sgg[s];
        float t0 = n1b2[0], t1 = n1b2[1];
#pragma unroll
        for (int m = 0; m < 32; ++m) {
            float hm = fmaf(sg, n1w1[m], n1b1[m]);
            hm = hm / (1.f + __expf(-hm));
            t0 = fmaf(hm, n1w2[m], t0);
            t1 = fmaf(hm, n1w2[32 + m], t1);
        }
        float u0 = n2b2[0], u1 = n2b2[1];
#pragma unroll
        for (int m = 0; m < 32; ++m) {
            float hm = za * n2w1[4 * m] + zb * n2w1[4 * m + 1]
                     + xa * n2w1[4 * m + 2] + xb * n2w1[4 * m + 3] + n2b1[m];
            hm = hm / (1.f + __expf(-hm));
            u0 = fmaf(hm, n2w2[m], u0);
            u1 = fmaf(hm, n2w2[32 + m], u1);
        }
        zz0 = u0 + t0; zz1 = u1 + t1;
    }

    f32x4 h[8][2];

    for (int L = 0; L < 16; ++L) {
        const float* rec = recs + L * 40;
        float out0, ldp0;
        rqs_knots(zz0, rec, out0, ldp0);
        if (lane < 32) o0w[ml] = out0;      // intra-wave: lgkm ordering only

        // ---- h init in registers + packed relu write into A ----
        {
            float o0a = o0w[tx];            // m_local = tx       (mt = 0)
            float o0b = o0w[16 + tx];       // m_local = 16 + tx  (mt = 1)
#pragma unroll
            for (int nt = 0; nt < 8; ++nt) {
                int n0 = nt * 16 + (q << 2);
                float4 w0v = *(const float4*)(ws0 + L * 128 + n0);
                float4 b0v = *(const float4*)(b0g + L * 128 + n0);
#pragma unroll
                for (int mt = 0; mt < 2; ++mt) {
                    float o0 = mt ? o0b : o0a;
                    f32x4 v;
                    v[0] = fmaf(o0, w0v.x, b0v.x);
                    v[1] = fmaf(o0, w0v.y, b0v.y);
                    v[2] = fmaf(o0, w0v.z, b0v.z);
                    v[3] = fmaf(o0, w0v.w, b0v.w);
                    h[nt][mt] = v;
                    v[0] = fmaxf(v[0], 0.f); v[1] = fmaxf(v[1], 0.f);
                    v[2] = fmaxf(v[2], 0.f); v[3] = fmaxf(v[3], 0.f);
                    storeA(A, mt, tx, q, tx7, nt, v);
                }
            }
        }

        const char* sw = wsW + L * 131072;
        const float* bb = bresg + (L << 9);

        res_stage<0, 1>(A, sw,           sw + 32768,    4096, bb,       h, wfA, wfB, q, tx, lane);
        res_stage<1, 1>(A, sw + 32768,   sw + 65536,    4096, bb + 128, h, wfA, wfB, q, tx, lane);
        res_stage<0, 1>(A, sw + 65536,   sw + 98304,    4096, bb + 256, h, wfA, wfB, q, tx, lane);
        res_stage<1, 0>(A, sw + 98304,   wsF + (L << 13), 1024, bb + 384, h, wfA, wfB, q, tx, lane);

        // ---- projection: p1^T[o][m]; Wf frags already resident in wfA ----
        {
            f32x4 pacc[2][2];
#pragma unroll
            for (int ot = 0; ot < 2; ++ot)
#pragma unroll
                for (int mt = 0; mt < 2; ++mt) pacc[ot][mt] = (f32x4){0.f, 0.f, 0.f, 0.f};
#pragma unroll
            for (int ks = 0; ks < 4; ++ks) {
                s16x8 bf[2];
#pragma unroll
                for (int mt = 0; mt < 2; ++mt)
                    bf[mt] = readB(A, mt, tx, q, tx7, ks);
#pragma unroll
                for (int ot = 0; ot < 2; ++ot)
#pragma unroll
                    for (int mt = 0; mt < 2; ++mt)
                        pacc[ot][mt] = __builtin_amdgcn_mfma_f32_16x16x32_bf16(wfA[ot * 4 + ks], bf[mt], pacc[ot][mt], 0, 0, 0);
            }
            // start next layer's stage0 ks0 group; proj epilogue + spline hide the latency
            int Ln = (L < 15) ? (L + 1) : 15;
            load_group(wfA, wsW + Ln * 131072, 4096, lane);

#pragma unroll
            for (int ot = 0; ot < 2; ++ot) {
                float4 bias = *(const float4*)(wsb + L * 32 + ot * 16 + (q << 2));
#pragma unroll
                for (int mt = 0; mt < 2; ++mt) {
                    int row = mt * 16 + tx;
                    float4 o;
                    o.x = pacc[ot][mt][0] + bias.x;
                    o.y = pacc[ot][mt][1] + bias.y;
                    o.z = pacc[ot][mt][2] + bias.z;
                    o.w = pacc[ot][mt][3] + bias.w;
                    *(float4*)(p1w + row * P1S + ot * 16 + (q << 2)) = o;
                }
            }
        }

        // ---- dim-1 spline + folded LU/permute (per owned sample, duplicated) ----
        {
            float pp[24];
            const float4* pr = (const float4*)(p1w + ml * P1S);
#pragma unroll
            for (int i = 0; i < 6; ++i) {
                float4 v4 = pr[i];
                pp[4 * i] = v4.x; pp[4 * i + 1] = v4.y; pp[4 * i + 2] = v4.z; pp[4 * i + 3] = v4.w;
            }
            float out1, ldp1;
            rqs_inv(zz1, pp, out1, ldp1);
            ld += ldp0 + ldp1;
            float v0 = out0 - rec[31], v1 = out1 - rec[32];
            zz0 = fmaf(v0, rec[27], v1 * rec[28]);
            zz1 = fmaf(v0, rec[29], v1 * rec[30]);
        }
    }

    if (lane < 32) {
        int s = sbase + ml;
        float ldc = *(const float*)(ws + LDC_OFF);
        outg[2 * s] = zz0;
        outg[2 * s + 1] = zz1;
        outg[2 * NBATCH + s] = ld - ldc;
    }
}

extern "C" void kernel_launch(void* const* d_in, const int* in_sizes, int n_in,
                              void* d_out, int out_size, void* d_ws, size_t ws_size,
                              hipStream_t stream)
{
    const float* z0g  = (const float*)d_in[0];
    const float* xg   = (const float*)d_in[1];
    const float* sgg  = (const float*)d_in[2];
    const float* n1w1 = (const float*)d_in[3];
    const float* n1b1 = (const float*)d_in[4];
    const float* n1w2 = (const float*)d_in[5];
    const float* n1b2 = (const float*)d_in[6];
    const float* n2w1 = (const float*)d_in[7];
    const float* n2b1 = (const float*)d_in[8];
    const float* n2w2 = (const float*)d_in[9];
    const float* n2b2 = (const float*)d_in[10];
    const float* W0g  = (const float*)d_in[11];
    const float* b0g  = (const float*)d_in[12];
    const float* Wres = (const float*)d_in[13];
    const float* bres = (const float*)d_in[14];
    const float* Wfg  = (const float*)d_in[15];
    const float* bfg  = (const float*)d_in[16];
    const float* lul  = (const float*)d_in[17];
    const float* luu  = (const float*)d_in[18];
    const float* lud  = (const float*)d_in[19];
    const float* lub  = (const float*)d_in[20];
    const int*   perms= (const int*)d_in[21];
    float* outg = (float*)d_out;

    nsf_prep<<<1024, 256, 0, stream>>>(Wres, Wfg, bfg, W0g, lul, luu, lud, lub, perms, (char*)d_ws);
    nsf_kernel<<<NBATCH / 128, 256, 0, stream>>>(z0g, xg, sgg,
                                                 n1w1, n1b1, n1w2, n1b2,
                                                 n2w1, n2b1, n2w2, n2b2,
                                                 b0g, bres,
                                                 (const char*)d_ws, outg);
}

// Round 6
// 1083.030 us; speedup vs baseline: 1.5198x; 1.5198x over previous
//
#include <hip/hip_runtime.h>
#include <math.h>

#define NBATCH 262144
#define INVSQH 0.08838834764831845f   // 1/sqrt(128)

typedef float f32x4 __attribute__((ext_vector_type(4)));
typedef short s16x8 __attribute__((ext_vector_type(8)));
typedef __bf16 bf16x2_t __attribute__((ext_vector_type(2)));

// ---- workspace layout (bytes) ----
#define WSR_OFF 0                 // Wres bf16 swizzled, half-K split: 16L*4st*2half*16384
#define WSF_OFF 2097152           // Wf padded [32][128] bf16 swizzled full-K: 16 * 8192
#define WS0_OFF 2228224           // W0 col0 packed: 16*128 f32
#define WSB_OFF 2236416           // proj bias padded: 16*32 f32
#define REC_OFF 2238464           // 16 * 40 f32 (cw9 ch9 d9 lu4 lub2)
#define LDC_OFF 2241024           // 1 f32: sum log-diag

// ---- LDS layout (bytes) ----
#define A_OFF   0                 // act: 128 rows * 256 B (bf16, swizzled 16B chunks)
#define BM_OFF  32768             // 2 x 16384 rotating weight-half buffers
#define O0_OFF  65536             // 128 f32
#define P1_OFF  66048             // 128 * 28 f32 = 14336
#define P1S     28
#define SMEM_BYTES 80384          // 2 blocks/CU

__device__ __forceinline__ float softplusf(float x) {
    // log1pf is a libcall; __logf(1+e) is 2 HW ops. |diff| ~1e-7 rel, fine vs threshold.
    return (x > 15.f) ? x : __logf(1.f + __expf(x));
}
__device__ __forceinline__ unsigned short f2bf(float x) {
    unsigned u = __float_as_uint(x);
    unsigned r = (u + 0x7FFFu + ((u >> 16) & 1u)) >> 16;   // RNE
    return (unsigned short)r;
}
// pack two fp32 -> bf16x2 dword, RNE (HW-verified rounding-identical to f2bf in R4/R5)
__device__ __forceinline__ unsigned pack2bf(float a, float b) {
#if __has_builtin(__builtin_amdgcn_cvt_pk_bf16_f32)
    bf16x2_t r = __builtin_amdgcn_cvt_pk_bf16_f32(a, b);
    return __builtin_bit_cast(unsigned, r);
#else
    return (unsigned)f2bf(a) | ((unsigned)f2bf(b) << 16);
#endif
}

__device__ __forceinline__ void rqs_solve(float y, float yc, float yk, float hk, float xk,
                                          float wk, float dk, float dk1,
                                          float& xout, float& ldout)
{
    float sk = hk / wk;
    float dy = yc - yk;
    float t2 = dk + dk1 - 2.f * sk;
    float av = dy * t2 + hk * (sk - dk);
    float bv = hk * dk - dy * t2;
    float cv = -sk * dy;
    float disc = fmaxf(bv * bv - 4.f * av * cv, 0.f);
    float theta = 2.f * cv / (-bv - sqrtf(disc));
    float xo = fmaf(theta, wk, xk);
    float om = 1.f - theta;
    float denom = fmaf(t2, theta * om, sk);
    float dnum = sk * sk * (dk1 * theta * theta + 2.f * sk * theta * om + dk * om * om);
    float ldf = __logf(dnum) - 2.f * __logf(denom);
    bool inside = (y >= -3.f) && (y <= 3.f);
    xout  = inside ? xo : y;
    ldout = inside ? -ldf : 0.f;
}

// full RQS inverse from raw params p[0..22] (dim-1, per-sample)
__device__ __forceinline__ void rqs_inv(float y, const float* __restrict__ p,
                                        float& xout, float& ldout)
{
    float uw[8], uh[8];
#pragma unroll
    for (int j = 0; j < 8; ++j) uw[j] = p[j] * INVSQH;
#pragma unroll
    for (int j = 0; j < 8; ++j) uh[j] = p[8 + j] * INVSQH;
    float mw = uw[0], mh = uh[0];
#pragma unroll
    for (int j = 1; j < 8; ++j) { mw = fmaxf(mw, uw[j]); mh = fmaxf(mh, uh[j]); }
    float ew[8], eh[8], sw = 0.f, sh = 0.f;
#pragma unroll
    for (int j = 0; j < 8; ++j) {
        ew[j] = __expf(uw[j] - mw); sw += ew[j];
        eh[j] = __expf(uh[j] - mh); sh += eh[j];
    }
    float isw = 0.992f / sw, ish = 0.992f / sh;
    float cw[9], ch[9];
    cw[0] = -3.f; ch[0] = -3.f;
    float aw = 0.f, ah = 0.f;
#pragma unroll
    for (int j = 0; j < 8; ++j) {
        aw += 0.001f + ew[j] * isw;
        ah += 0.001f + eh[j] * ish;
        cw[j + 1] = 6.f * aw - 3.f;
        ch[j + 1] = 6.f * ah - 3.f;
    }
    cw[8] = 3.f; ch[8] = 3.f;
    float d[9];
    d[0] = 1.f; d[8] = 1.f;
#pragma unroll
    for (int j = 0; j < 7; ++j) d[j + 1] = 0.001f + softplusf(p[16 + j]);

    float yc = fminf(fmaxf(y, -3.f), 3.f);
    float yk = ch[0], hk = ch[1] - ch[0], xk = cw[0], wk = cw[1] - cw[0];
    float dk = d[0], dk1 = d[1];
#pragma unroll
    for (int j = 1; j < 8; ++j) {
        bool cge = (yc >= ch[j]);
        yk  = cge ? ch[j] : yk;
        hk  = cge ? (ch[j + 1] - ch[j]) : hk;
        xk  = cge ? cw[j] : xk;
        wk  = cge ? (cw[j + 1] - cw[j]) : wk;
        dk  = cge ? d[j] : dk;
        dk1 = cge ? d[j + 1] : dk1;
    }
    rqs_solve(y, yc, yk, hk, xk, wk, dk, dk1, xout, ldout);
}

// RQS inverse from precomputed knots rec = {cw[9], ch[9], d[9]} (dim-0, per-layer const)
__device__ __forceinline__ void rqs_knots(float y, const float* __restrict__ rec,
                                          float& xout, float& ldout)
{
    const float* cw = rec;
    const float* ch = rec + 9;
    const float* dd = rec + 18;
    float yc = fminf(fmaxf(y, -3.f), 3.f);
    float yk = ch[0], hk = ch[1] - ch[0], xk = cw[0], wk = cw[1] - cw[0];
    float dk = dd[0], dk1 = dd[1];
#pragma unroll
    for (int j = 1; j < 8; ++j) {
        bool cge = (yc >= ch[j]);
        yk  = cge ? ch[j] : yk;
        hk  = cge ? (ch[j + 1] - ch[j]) : hk;
        xk  = cge ? cw[j] : xk;
        wk  = cge ? (cw[j + 1] - cw[j]) : wk;
        dk  = cge ? dd[j] : dk;
        dk1 = cge ? dd[j + 1] : dk1;
    }
    rqs_solve(y, yc, yk, hk, xk, wk, dk, dk1, xout, ldout);
}

// async global->LDS, 16B/lane; wave w stages its quarter of nbytes.
__device__ __forceinline__ void prefetch_lds(const char* src, char* dst, int nbytes,
                                             int w, int lane)
{
    int slice = nbytes >> 2;
    const char* s = src + w * slice + lane * 16;
    char* d = dst + w * slice;
    for (int i = 0; i < slice; i += 1024)
        __builtin_amdgcn_global_load_lds(
            (const __attribute__((address_space(1))) unsigned int*)(s + i),
            (__attribute__((address_space(3))) unsigned int*)(d + i), 16, 0, 0);
}

// packed bf16x4 store of one D-tile fragment into act buffer.
__device__ __forceinline__ void pack_store(char* A, int m, int tn2, int i, int q, int tx7, f32x4 v)
{
    unsigned d0 = pack2bf(v[0], v[1]);
    unsigned d1 = pack2bf(v[2], v[3]);
    int chunk = ((tn2 << 3) + (i << 1) + (q >> 1)) ^ tx7;
    *(uint2*)(A + (m << 8) + (chunk << 4) + ((q & 1) << 3)) = make_uint2(d0, d1);
}

// One 128x128x128 transposed MFMA stage: out^T[n][m] = sum_k W[n][k] act[m][k].
// Wave w: tn2=w>>1 (n-half), tm2=w&1 (m-half), 4x4 tiles of 16x16.
// Two K-phases; phase p reads its weight half from LDS, prefetches the next item
// into the other buffer. Bias (+h) folded into acc init (rounding-identical, R4-proven).
template <int BSTAGE, int RELUOUT>
__device__ __forceinline__ void res_stage(char* A, char* bm0, char* bm1,
                                          const char* pf1, const char* pf2, int pf2n,
                                          const float* biasrow, f32x4 h[4][4],
                                          int tn2, int tm2, int q, int tx, int w, int lane)
{
    const int tx7 = tx & 7;
    f32x4 acc[4][4];
#pragma unroll
    for (int i = 0; i < 4; ++i) {
        float4 bv = *(const float4*)(biasrow + tn2 * 64 + i * 16 + (q << 2));
        f32x4 b; b[0] = bv.x; b[1] = bv.y; b[2] = bv.z; b[3] = bv.w;
#pragma unroll
        for (int j = 0; j < 4; ++j)
            acc[i][j] = BSTAGE ? (h[i][j] + b) : b;
    }

#pragma unroll
    for (int ph = 0; ph < 2; ++ph) {
        const char* bm = ph ? bm1 : bm0;
        if (ph == 0) prefetch_lds(pf1, bm1, 16384, w, lane);
        else         prefetch_lds(pf2, bm0, pf2n, w, lane);
#pragma unroll
        for (int kt = 0; kt < 2; ++kt) {
            int ktg = (ph << 1) + kt;
            int ccW = ((kt << 2) + q) ^ tx7;       // chunk within 128B half-row
            int ccA = ((ktg << 2) + q) ^ tx7;      // chunk within 256B act row
            s16x8 wf[4], af[4];
#pragma unroll
            for (int i = 0; i < 4; ++i)
                wf[i] = *(const s16x8*)(bm + ((tn2 * 64 + i * 16 + tx) << 7) + (ccW << 4));
#pragma unroll
            for (int j = 0; j < 4; ++j)
                af[j] = *(const s16x8*)(A + ((tm2 * 64 + j * 16 + tx) << 8) + (ccA << 4));
#pragma unroll
            for (int i = 0; i < 4; ++i)
#pragma unroll
                for (int j = 0; j < 4; ++j)
                    acc[i][j] = __builtin_amdgcn_mfma_f32_16x16x32_bf16(wf[i], af[j], acc[i][j], 0, 0, 0);
        }
        __syncthreads();    // phase barrier: also forces this phase's prefetch landed
    }

#pragma unroll
    for (int i = 0; i < 4; ++i)
#pragma unroll
        for (int j = 0; j < 4; ++j) {
            if (BSTAGE) h[i][j] = acc[i][j];
            f32x4 v = acc[i][j];
            if (RELUOUT) {
                v[0] = fmaxf(v[0], 0.f); v[1] = fmaxf(v[1], 0.f);
                v[2] = fmaxf(v[2], 0.f); v[3] = fmaxf(v[3], 0.f);
            }
            pack_store(A, tm2 * 64 + j * 16 + tx, tn2, i, q, tx7, v);
        }
    __syncthreads();
}

// ---------------- prep kernel (identical to the 1208us R3 version) ----------------
extern "C" __global__ void nsf_prep(const float* __restrict__ Wresg, const float* __restrict__ Wfg,
                                    const float* __restrict__ bfg, const float* __restrict__ W0g,
                                    const float* __restrict__ lulg, const float* __restrict__ luug,
                                    const float* __restrict__ ludg, const float* __restrict__ lubg,
                                    const int* __restrict__ permsg, char* __restrict__ ws)
{
    int t = blockIdx.x * blockDim.x + threadIdx.x;
    int stride = gridDim.x * blockDim.x;
    unsigned short* wr = (unsigned short*)(ws + WSR_OFF);
    unsigned short* wf = (unsigned short*)(ws + WSF_OFF);
    float* ws0 = (float*)(ws + WS0_OFF);
    float* wsb = (float*)(ws + WSB_OFF);

    // Wres: stage sidx = L*4 + st; split K into halves of 64
    for (int e = t; e < 16 * 4 * 16384; e += stride) {
        int sidx = e >> 14;
        int rem = e & 16383;
        int o = rem >> 7, k = rem & 127;
        int half = k >> 6, kr = k & 63;
        wr[(sidx * 2 + half) * 8192 + o * 64 + (((kr >> 3) ^ (o & 7)) << 3) + (kr & 7)]
            = f2bf(Wresg[e]);
    }
    // Wf padded to 32 rows, full-K 256B rows
    for (int e = t; e < 16 * 32 * 128; e += stride) {
        int L = e >> 12;
        int rem = e & 4095;
        int o = rem >> 7, k = rem & 127;
        float x = (o < 23) ? Wfg[(L * 46 + 23 + o) * 128 + k] : 0.f;
        wf[L * 4096 + o * 128 + (((k >> 3) ^ (o & 7)) << 3) + (k & 7)] = f2bf(x);
    }
    for (int e = t; e < 16 * 128; e += stride)
        ws0[e] = W0g[2 * e];
    for (int e = t; e < 16 * 32; e += stride) {
        int L = e >> 5, o = e & 31;
        wsb[e] = (o < 23) ? bfg[L * 46 + 23 + o] : 0.f;
    }
    if (t < 16) {
        int L = t;
        float* rec = (float*)(ws + REC_OFF) + L * 40;
        const float* p = bfg + L * 46;
        for (int half = 0; half < 2; ++half) {
            float u[8], m = -1e30f;
            for (int j = 0; j < 8; ++j) { u[j] = p[half * 8 + j] * INVSQH; m = fmaxf(m, u[j]); }
            float e[8], s = 0.f;
            for (int j = 0; j < 8; ++j) { e[j] = expf(u[j] - m); s += e[j]; }
            float cum = 0.f;
            rec[half * 9 + 0] = -3.f;
            for (int j = 0; j < 8; ++j) {
                cum += 0.001f + 0.992f * e[j] / s;
                rec[half * 9 + 1 + j] = 6.f * cum - 3.f;
            }
            rec[half * 9 + 8] = 3.f;
        }
        rec[18] = 1.f; rec[26] = 1.f;
        for (int j = 0; j < 7; ++j) {
            float x = p[16 + j];
            rec[19 + j] = 0.001f + ((x > 15.f) ? x : log1pf(expf(x)));
        }
        float x0 = ludg[2 * L], x1 = ludg[2 * L + 1];
        float dg0 = 0.001f + ((x0 > 15.f) ? x0 : log1pf(expf(x0)));
        float dg1 = 0.001f + ((x1 > 15.f) ? x1 : log1pf(expf(x1)));
        float ll = lulg[L], uu = luug[L];
        float det = dg0 * dg1;
        float c00 = (ll * uu + dg1) / det, c01 = -uu / det;
        float c10 = -ll / dg1, c11 = 1.f / dg1;
        int pa = permsg[2 * L], pb = permsg[2 * L + 1];
        rec[27] = pa ? c10 : c00; rec[28] = pa ? c11 : c01;
        rec[29] = pb ? c10 : c00; rec[30] = pb ? c11 : c01;
        rec[31] = lubg[2 * L];    rec[32] = lubg[2 * L + 1];
    }
    if (t == 16) {
        float s = 0.f;
        for (int L = 0; L < 16; ++L) {
            float x0 = ludg[2 * L], x1 = ludg[2 * L + 1];
            float dg0 = 0.001f + ((x0 > 15.f) ? x0 : log1pf(expf(x0)));
            float dg1 = 0.001f + ((x1 > 15.f) ? x1 : log1pf(expf(x1)));
            s += logf(dg0) + logf(dg1);
        }
        *(float*)(ws + LDC_OFF) = s;
    }
}

// ---------------- main fused kernel ----------------
extern "C" __global__ __launch_bounds__(256, 2)
void nsf_kernel(const float* __restrict__ z0g, const float* __restrict__ xg,
                const float* __restrict__ sgg,
                const float* __restrict__ n1w1, const float* __restrict__ n1b1,
                const float* __restrict__ n1w2, const float* __restrict__ n1b2,
                const float* __restrict__ n2w1, const float* __restrict__ n2b1,
                const float* __restrict__ n2w2, const float* __restrict__ n2b2,
                const float* __restrict__ b0g,  const float* __restrict__ bresg,
                const char* __restrict__ ws, float* __restrict__ outg)
{
    extern __shared__ char smem[];
    char* A  = smem + A_OFF;
    char* BM = smem + BM_OFF;
    float* out0sh = (float*)(smem + O0_OFF);
    float* p1f = (float*)(smem + P1_OFF);

    const int tid = threadIdx.x;
    const int lane = tid & 63, w = tid >> 6;
    const int q = lane >> 4, tx = lane & 15, tx7 = tx & 7;
    const int tn2 = w >> 1, tm2 = w & 1;
    const int sbase = blockIdx.x * 128;

    const char* wsW = ws + WSR_OFF;
    const char* wsF = ws + WSF_OFF;
    const float* ws0 = (const float*)(ws + WS0_OFF);
    const float* wsb = (const float*)(ws + WSB_OFF);
    const float* recs = (const float*)(ws + REC_OFF);

    // stage layer-0 stage-0 k-half-0 while conditioning MLP runs (item 0 -> buf 0)
    prefetch_lds(wsW, BM, 16384, w, lane);

    float zz0 = 0.f, zz1 = 0.f, ld = 0.f;
    if (tid < 128) {
        int s = sbase + tid;
        float za = z0g[2 * s], zb = z0g[2 * s + 1];
        float xa = xg[2 * s],  xb = xg[2 * s + 1];
        float sg = sgg[s];
        float t0 = n1b2[0], t1 = n1b2[1];
#pragma unroll
        for (int m = 0; m < 32; ++m) {
            float hm = fmaf(sg, n1w1[m], n1b1[m]);
            hm = hm / (1.f + __expf(-hm));
            t0 = fmaf(hm, n1w2[m], t0);
            t1 = fmaf(hm, n1w2[32 + m], t1);
        }
        float u0 = n2b2[0], u1 = n2b2[1];
#pragma unroll
        for (int m = 0; m < 32; ++m) {
            float hm = za * n2w1[4 * m] + zb * n2w1[4 * m + 1]
                     + xa * n2w1[4 * m + 2] + xb * n2w1[4 * m + 3] + n2b1[m];
            hm = hm / (1.f + __expf(-hm));
            u0 = fmaf(hm, n2w2[m], u0);
            u1 = fmaf(hm, n2w2[32 + m], u1);
        }
        zz0 = u0 + t0; zz1 = u1 + t1;
    }

    f32x4 h[4][4];
    int pbuf = 0;   // parity of the buffer holding the current layer's first item

    for (int L = 0; L < 16; ++L) {
        const float* rec = recs + L * 40;
        float out0 = 0.f, ldp0 = 0.f;
        if (tid < 128) {
            rqs_knots(zz0, rec, out0, ldp0);
            out0sh[tid] = out0;
        }
        __syncthreads();                                   // B0

        // ---- h init in registers + packed relu write into A ----
        {
#pragma unroll
            for (int i = 0; i < 4; ++i) {
                int n0 = tn2 * 64 + i * 16 + (q << 2);
                float4 w0v = *(const float4*)(ws0 + L * 128 + n0);
                float4 b0v = *(const float4*)(b0g + L * 128 + n0);
#pragma unroll
                for (int j = 0; j < 4; ++j) {
                    int m = tm2 * 64 + j * 16 + tx;
                    float o0 = out0sh[m];
                    f32x4 v;
                    v[0] = fmaf(o0, w0v.x, b0v.x);
                    v[1] = fmaf(o0, w0v.y, b0v.y);
                    v[2] = fmaf(o0, w0v.z, b0v.z);
                    v[3] = fmaf(o0, w0v.w, b0v.w);
                    h[i][j] = v;
                    v[0] = fmaxf(v[0], 0.f); v[1] = fmaxf(v[1], 0.f);
                    v[2] = fmaxf(v[2], 0.f); v[3] = fmaxf(v[3], 0.f);
                    pack_store(A, m, tn2, i, q, tx7, v);
                }
            }
        }
        __syncthreads();                                   // B1

        char* b0p = BM + pbuf * 16384;
        char* b1p = BM + (pbuf ^ 1) * 16384;
        const char* sw = wsW + L * 4 * 32768;
        const float* bb = bresg + L * 4 * 128;

        res_stage<0, 1>(A, b0p, b1p, sw + 16384,  sw + 32768,  16384, bb + 0,   h, tn2, tm2, q, tx, w, lane);
        res_stage<1, 1>(A, b0p, b1p, sw + 49152,  sw + 65536,  16384, bb + 128, h, tn2, tm2, q, tx, w, lane);
        res_stage<0, 1>(A, b0p, b1p, sw + 81920,  sw + 98304,  16384, bb + 256, h, tn2, tm2, q, tx, w, lane);
        res_stage<1, 0>(A, b0p, b1p, sw + 114688, wsF + L * 8192, 8192, bb + 384, h, tn2, tm2, q, tx, w, lane);

        // ---- projection: p1^T[o][m], Wf in b0p (8 KB), act in A ----
        {
            if (L < 15) prefetch_lds(wsW + (L + 1) * 4 * 32768, b1p, 16384, w, lane);
            f32x4 pacc[2][2];
#pragma unroll
            for (int ct = 0; ct < 2; ++ct)
#pragma unroll
                for (int jm = 0; jm < 2; ++jm) pacc[ct][jm] = (f32x4){0.f, 0.f, 0.f, 0.f};
#pragma unroll
            for (int ktg = 0; ktg < 4; ++ktg) {
                int ccA = ((ktg << 2) + q) ^ tx7;
                s16x8 wfr[2], afr[2];
#pragma unroll
                for (int ct = 0; ct < 2; ++ct)
                    wfr[ct] = *(const s16x8*)(b0p + ((ct * 16 + tx) << 8) + (ccA << 4));
#pragma unroll
                for (int jm = 0; jm < 2; ++jm)
                    afr[jm] = *(const s16x8*)(A + (((w << 5) + jm * 16 + tx) << 8) + (ccA << 4));
#pragma unroll
                for (int ct = 0; ct < 2; ++ct)
#pragma unroll
                    for (int jm = 0; jm < 2; ++jm)
                        pacc[ct][jm] = __builtin_amdgcn_mfma_f32_16x16x32_bf16(wfr[ct], afr[jm], pacc[ct][jm], 0, 0, 0);
            }
#pragma unroll
            for (int ct = 0; ct < 2; ++ct) {
                if (ct == 0 || q < 2) {
                    float4 bias = *(const float4*)(wsb + L * 32 + ct * 16 + (q << 2));
#pragma unroll
                    for (int jm = 0; jm < 2; ++jm) {
                        int m = (w << 5) + jm * 16 + tx;
                        float4 o;
                        o.x = pacc[ct][jm][0] + bias.x;
                        o.y = pacc[ct][jm][1] + bias.y;
                        o.z = pacc[ct][jm][2] + bias.z;
                        o.w = pacc[ct][jm][3] + bias.w;
                        *(float4*)(p1f + m * P1S + ct * 16 + (q << 2)) = o;
                    }
                }
            }
        }
        __syncthreads();                                   // proj-end

        // ---- dim-1 spline + folded LU/permute ----
        if (tid < 128) {
            float pp[24];
            const float4* pr = (const float4*)(p1f + tid * P1S);
#pragma unroll
            for (int i = 0; i < 6; ++i) {
                float4 v4 = pr[i];
                pp[4 * i] = v4.x; pp[4 * i + 1] = v4.y; pp[4 * i + 2] = v4.z; pp[4 * i + 3] = v4.w;
            }
            float out1, ldp1;
            rqs_inv(zz1, pp, out1, ldp1);
            ld += ldp0 + ldp1;
            float v0 = out0 - rec[31], v1 = out1 - rec[32];
            zz0 = fmaf(v0, rec[27], v1 * rec[28]);
            zz1 = fmaf(v0, rec[29], v1 * rec[30]);
        }
        pbuf ^= 1;   // 9 weight items per layer -> parity flips
    }

    if (tid < 128) {
        int s = sbase + tid;
        float ldc = *(const float*)(ws + LDC_OFF);
        outg[2 * s] = zz0;
        outg[2 * s + 1] = zz1;
        outg[2 * NBATCH + s] = ld - ldc;
    }
}

extern "C" void kernel_launch(void* const* d_in, const int* in_sizes, int n_in,
                              void* d_out, int out_size, void* d_ws, size_t ws_size,
                              hipStream_t stream)
{
    const float* z0g  = (const float*)d_in[0];
    const float* xg   = (const float*)d_in[1];
    const float* sgg  = (const float*)d_in[2];
    const float* n1w1 = (const float*)d_in[3];
    const float* n1b1 = (const float*)d_in[4];
    const float* n1w2 = (const float*)d_in[5];
    const float* n1b2 = (const float*)d_in[6];
    const float* n2w1 = (const float*)d_in[7];
    const float* n2b1 = (const float*)d_in[8];
    const float* n2w2 = (const float*)d_in[9];
    const float* n2b2 = (const float*)d_in[10];
    const float* W0g  = (const float*)d_in[11];
    const float* b0g  = (const float*)d_in[12];
    const float* Wres = (const float*)d_in[13];
    const float* bres = (const float*)d_in[14];
    const float* Wfg  = (const float*)d_in[15];
    const float* bfg  = (const float*)d_in[16];
    const float* lul  = (const float*)d_in[17];
    const float* luu  = (const float*)d_in[18];
    const float* lud  = (const float*)d_in[19];
    const float* lub  = (const float*)d_in[20];
    const int*   perms= (const int*)d_in[21];
    float* outg = (float*)d_out;

    hipFuncSetAttribute((const void*)nsf_kernel,
                        hipFuncAttributeMaxDynamicSharedMemorySize, SMEM_BYTES);

    nsf_prep<<<1024, 256, 0, stream>>>(Wres, Wfg, bfg, W0g, lul, luu, lud, lub, perms, (char*)d_ws);
    nsf_kernel<<<NBATCH / 128, 256, SMEM_BYTES, stream>>>(z0g, xg, sgg,
                                                          n1w1, n1b1, n1w2, n1b2,
                                                          n2w1, n2b1, n2w2, n2b2,
                                                          b0g, bres,
                                                          (const char*)d_ws, outg);
}

// Round 7
// 428.002 us; speedup vs baseline: 3.8458x; 2.5304x over previous
//
#include <hip/hip_runtime.h>
#include <math.h>

#define NBATCH 262144
#define INVSQH 0.08838834764831845f   // 1/sqrt(128)

#define NPT   2048                    // points per layer (power of 2, bitonic-sorted)
#define TROW  24                      // table row stride (23 params + pad)

// ---- workspace layout (bytes) ----
#define BP_OFF  0                           // breakpoints: 16 * 2048 f32 = 131072
#define TAB_OFF 131072                      // table: 16 * 2048 * 24 f32 = 3145728
#define REC_OFF 3276800                     // 16 * 40 f32 (cw9 ch9 d9 lu4 lub2)
#define LDC_OFF 3279360                     // 1 f32: sum log-diag
// total ~3.13 MB of d_ws

__device__ __forceinline__ float softplusf(float x) {
    return (x > 15.f) ? x : __logf(1.f + __expf(x));
}

__device__ __forceinline__ void rqs_solve(float y, float yc, float yk, float hk, float xk,
                                          float wk, float dk, float dk1,
                                          float& xout, float& ldout)
{
    float sk = hk / wk;
    float dy = yc - yk;
    float t2 = dk + dk1 - 2.f * sk;
    float av = dy * t2 + hk * (sk - dk);
    float bv = hk * dk - dy * t2;
    float cv = -sk * dy;
    float disc = fmaxf(bv * bv - 4.f * av * cv, 0.f);
    float theta = 2.f * cv / (-bv - sqrtf(disc));
    float xo = fmaf(theta, wk, xk);
    float om = 1.f - theta;
    float denom = fmaf(t2, theta * om, sk);
    float dnum = sk * sk * (dk1 * theta * theta + 2.f * sk * theta * om + dk * om * om);
    float ldf = __logf(dnum) - 2.f * __logf(denom);
    bool inside = (y >= -3.f) && (y <= 3.f);
    xout  = inside ? xo : y;
    ldout = inside ? -ldf : 0.f;
}

// full RQS inverse from raw params p[0..22] (dim-1, per-sample)
__device__ __forceinline__ void rqs_inv(float y, const float* __restrict__ p,
                                        float& xout, float& ldout)
{
    float uw[8], uh[8];
#pragma unroll
    for (int j = 0; j < 8; ++j) uw[j] = p[j] * INVSQH;
#pragma unroll
    for (int j = 0; j < 8; ++j) uh[j] = p[8 + j] * INVSQH;
    float mw = uw[0], mh = uh[0];
#pragma unroll
    for (int j = 1; j < 8; ++j) { mw = fmaxf(mw, uw[j]); mh = fmaxf(mh, uh[j]); }
    float ew[8], eh[8], sw = 0.f, sh = 0.f;
#pragma unroll
    for (int j = 0; j < 8; ++j) {
        ew[j] = __expf(uw[j] - mw); sw += ew[j];
        eh[j] = __expf(uh[j] - mh); sh += eh[j];
    }
    float isw = 0.992f / sw, ish = 0.992f / sh;
    float cw[9], ch[9];
    cw[0] = -3.f; ch[0] = -3.f;
    float aw = 0.f, ah = 0.f;
#pragma unroll
    for (int j = 0; j < 8; ++j) {
        aw += 0.001f + ew[j] * isw;
        ah += 0.001f + eh[j] * ish;
        cw[j + 1] = 6.f * aw - 3.f;
        ch[j + 1] = 6.f * ah - 3.f;
    }
    cw[8] = 3.f; ch[8] = 3.f;
    float d[9];
    d[0] = 1.f; d[8] = 1.f;
#pragma unroll
    for (int j = 0; j < 7; ++j) d[j + 1] = 0.001f + softplusf(p[16 + j]);

    float yc = fminf(fmaxf(y, -3.f), 3.f);
    float yk = ch[0], hk = ch[1] - ch[0], xk = cw[0], wk = cw[1] - cw[0];
    float dk = d[0], dk1 = d[1];
#pragma unroll
    for (int j = 1; j < 8; ++j) {
        bool cge = (yc >= ch[j]);
        yk  = cge ? ch[j] : yk;
        hk  = cge ? (ch[j + 1] - ch[j]) : hk;
        xk  = cge ? cw[j] : xk;
        wk  = cge ? (cw[j + 1] - cw[j]) : wk;
        dk  = cge ? d[j] : dk;
        dk1 = cge ? d[j + 1] : dk1;
    }
    rqs_solve(y, yc, yk, hk, xk, wk, dk, dk1, xout, ldout);
}

// RQS inverse from precomputed knots rec = {cw[9], ch[9], d[9]} (dim-0, per-layer const)
__device__ __forceinline__ void rqs_knots(float y, const float* __restrict__ rec,
                                          float& xout, float& ldout)
{
    const float* cw = rec;
    const float* ch = rec + 9;
    const float* dd = rec + 18;
    float yc = fminf(fmaxf(y, -3.f), 3.f);
    float yk = ch[0], hk = ch[1] - ch[0], xk = cw[0], wk = cw[1] - cw[0];
    float dk = dd[0], dk1 = dd[1];
#pragma unroll
    for (int j = 1; j < 8; ++j) {
        bool cge = (yc >= ch[j]);
        yk  = cge ? ch[j] : yk;
        hk  = cge ? (ch[j + 1] - ch[j]) : hk;
        xk  = cge ? cw[j] : xk;
        wk  = cge ? (cw[j + 1] - cw[j]) : wk;
        dk  = cge ? dd[j] : dk;
        dk1 = cge ? dd[j + 1] : dk1;
    }
    rqs_solve(y, yc, yk, hk, xk, wk, dk, dk1, xout, ldout);
}

// ------------- kernel 1: build sorted breakpoint list + per-layer constants -------------
// one block per layer. Points: dense grid [-8.8,8.8]/0.0125 (1408), coarse +-[9.05,56.8]/0.25
// (2x192), exact gate-1 crossings -b0/a (128, clamped), pad. Bitonic sort in LDS.
extern "C" __global__ __launch_bounds__(256)
void nsf_sort(const float* __restrict__ W0g, const float* __restrict__ b0g,
              const float* __restrict__ bfg,
              const float* __restrict__ lulg, const float* __restrict__ luug,
              const float* __restrict__ ludg, const float* __restrict__ lubg,
              const int* __restrict__ permsg, char* __restrict__ ws)
{
    __shared__ float key[NPT];
    const int L = blockIdx.x;
    const int tid = threadIdx.x;
    float* bpg = (float*)(ws + BP_OFF);

    for (int i = tid; i < NPT; i += 256) {
        float v;
        if (i < 1408) {
            v = -8.8f + i * 0.0125f;
        } else if (i < 1600) {
            v = -56.8f + (i - 1408) * 0.25f;
        } else if (i < 1792) {
            v = 9.05f + (i - 1600) * 0.25f;
        } else if (i < 1920) {
            int k = i - 1792;
            float a = W0g[L * 256 + 2 * k];
            float c = b0g[L * 128 + k];
            float x = -c / a;
            v = (fabsf(x) < 56.0f) ? x : (57.0f + k * 0.01f);   // NaN/inf -> pad
        } else {
            v = 58.5f + (i - 1920) * 0.01f;
        }
        key[i] = v;
    }
    __syncthreads();

    // bitonic sort ascending, n = 2048
    for (int k = 2; k <= NPT; k <<= 1) {
        for (int j = k >> 1; j > 0; j >>= 1) {
            for (int i = tid; i < NPT; i += 256) {
                int ixj = i ^ j;
                if (ixj > i) {
                    float a = key[i], b = key[ixj];
                    bool up = ((i & k) == 0);
                    if (up ? (a > b) : (a < b)) { key[i] = b; key[ixj] = a; }
                }
            }
            __syncthreads();
        }
    }
    for (int i = tid; i < NPT; i += 256)
        bpg[L * NPT + i] = key[i];

    // per-layer constants (dim-0 spline knots + folded LU/perm), verbatim from R6 prep
    if (tid == 0) {
        float* rec = (float*)(ws + REC_OFF) + L * 40;
        const float* p = bfg + L * 46;
        for (int half = 0; half < 2; ++half) {
            float u[8], m = -1e30f;
            for (int j = 0; j < 8; ++j) { u[j] = p[half * 8 + j] * INVSQH; m = fmaxf(m, u[j]); }
            float e[8], s = 0.f;
            for (int j = 0; j < 8; ++j) { e[j] = expf(u[j] - m); s += e[j]; }
            float cum = 0.f;
            rec[half * 9 + 0] = -3.f;
            for (int j = 0; j < 8; ++j) {
                cum += 0.001f + 0.992f * e[j] / s;
                rec[half * 9 + 1 + j] = 6.f * cum - 3.f;
            }
            rec[half * 9 + 8] = 3.f;
        }
        rec[18] = 1.f; rec[26] = 1.f;
        for (int j = 0; j < 7; ++j) {
            float x = p[16 + j];
            rec[19 + j] = 0.001f + ((x > 15.f) ? x : log1pf(expf(x)));
        }
        float x0 = ludg[2 * L], x1 = ludg[2 * L + 1];
        float dg0 = 0.001f + ((x0 > 15.f) ? x0 : log1pf(expf(x0)));
        float dg1 = 0.001f + ((x1 > 15.f) ? x1 : log1pf(expf(x1)));
        float ll = lulg[L], uu = luug[L];
        float det = dg0 * dg1;
        float c00 = (ll * uu + dg1) / det, c01 = -uu / det;
        float c10 = -ll / dg1, c11 = 1.f / dg1;
        int pa = permsg[2 * L], pb = permsg[2 * L + 1];
        rec[27] = pa ? c10 : c00; rec[28] = pa ? c11 : c01;
        rec[29] = pb ? c10 : c00; rec[30] = pb ? c11 : c01;
        rec[31] = lubg[2 * L];    rec[32] = lubg[2 * L + 1];
    }
    if (L == 0 && tid == 32) {
        float s = 0.f;
        for (int l2 = 0; l2 < 16; ++l2) {
            float x0 = ludg[2 * l2], x1 = ludg[2 * l2 + 1];
            float dg0 = 0.001f + ((x0 > 15.f) ? x0 : log1pf(expf(x0)));
            float dg1 = 0.001f + ((x1 > 15.f) ? x1 : log1pf(expf(x1)));
            s += logf(dg0) + logf(dg1);
        }
        *(float*)(ws + LDC_OFF) = s;
    }
}

// ------------- kernel 2: evaluate F_L(s) = p1[23] at every breakpoint, exact f32 -------------
// 1024 blocks = 16 layers x 64 point-chunks of 32. 256 threads = 64 unit-pairs x 4 point-octets.
extern "C" __global__ __launch_bounds__(256, 4)
void nsf_eval(const float* __restrict__ Wresg, const float* __restrict__ bresg,
              const float* __restrict__ Wfg,  const float* __restrict__ bfg,
              const float* __restrict__ W0g,  const float* __restrict__ b0g,
              char* __restrict__ ws)
{
    __shared__ float S[32];
    __shared__ float H[128 * 36];     // raw residual carrier (pad 36: 16B-aligned rows)
    __shared__ float R[128 * 36];     // relu'd matvec input

    const float* bpg = (const float*)(ws + BP_OFF);
    float* tab = (float*)(ws + TAB_OFF);
    const int L  = blockIdx.x >> 6;
    const int pb = (blockIdx.x & 63) << 5;
    const int tid = threadIdx.x;
    const int u2 = tid & 63, g = tid >> 6, p0 = g << 3;

    if (tid < 32) S[tid] = bpg[L * NPT + pb + tid];
    __syncthreads();

    // stage 0: H = a*s + c ; R = relu(H)
#pragma unroll
    for (int hf = 0; hf < 2; ++hf) {
        int u = u2 + (hf << 6);
        float a = W0g[L * 256 + 2 * u];
        float c = b0g[L * 128 + u];
#pragma unroll
        for (int p = 0; p < 8; ++p) {
            float h = fmaf(a, S[p0 + p], c);
            H[u * 36 + p0 + p] = h;
            R[u * 36 + p0 + p] = fmaxf(h, 0.f);
        }
    }
    __syncthreads();

    // 4 matvec stages: st0: R=relu(W1 R+b1); st1: H+=W2 R+b2, R=relu(H);
    //                  st2: R=relu(W3 R+b3); st3: H+=W4 R+b4.
    for (int st = 0; st < 4; ++st) {
        const float* W  = Wresg + (L * 4 + st) * 16384;
        const float* bv = bresg + L * 512 + st * 128;
        const float* Wr0 = W + u2 * 128;
        const float* Wr1 = W + (u2 + 64) * 128;
        float acc[2][8];
        {
            float b0v = bv[u2], b1v = bv[u2 + 64];
#pragma unroll
            for (int p = 0; p < 8; ++p) { acc[0][p] = b0v; acc[1][p] = b1v; }
        }
        for (int k4 = 0; k4 < 32; ++k4) {
            float4 wA = *(const float4*)(Wr0 + (k4 << 2));
            float4 wB = *(const float4*)(Wr1 + (k4 << 2));
            float wa4[4] = {wA.x, wA.y, wA.z, wA.w};
            float wb4[4] = {wB.x, wB.y, wB.z, wB.w};
#pragma unroll
            for (int kk = 0; kk < 4; ++kk) {
                const float* rr = &R[((k4 << 2) + kk) * 36 + p0];
                float4 r0 = *(const float4*)rr;
                float4 r1 = *(const float4*)(rr + 4);
                float wa = wa4[kk], wb = wb4[kk];
                acc[0][0] = fmaf(wa, r0.x, acc[0][0]);
                acc[0][1] = fmaf(wa, r0.y, acc[0][1]);
                acc[0][2] = fmaf(wa, r0.z, acc[0][2]);
                acc[0][3] = fmaf(wa, r0.w, acc[0][3]);
                acc[0][4] = fmaf(wa, r1.x, acc[0][4]);
                acc[0][5] = fmaf(wa, r1.y, acc[0][5]);
                acc[0][6] = fmaf(wa, r1.z, acc[0][6]);
                acc[0][7] = fmaf(wa, r1.w, acc[0][7]);
                acc[1][0] = fmaf(wb, r0.x, acc[1][0]);
                acc[1][1] = fmaf(wb, r0.y, acc[1][1]);
                acc[1][2] = fmaf(wb, r0.z, acc[1][2]);
                acc[1][3] = fmaf(wb, r0.w, acc[1][3]);
                acc[1][4] = fmaf(wb, r1.x, acc[1][4]);
                acc[1][5] = fmaf(wb, r1.y, acc[1][5]);
                acc[1][6] = fmaf(wb, r1.z, acc[1][6]);
                acc[1][7] = fmaf(wb, r1.w, acc[1][7]);
            }
        }
        __syncthreads();   // all R reads complete before overwrite
#pragma unroll
        for (int hf = 0; hf < 2; ++hf) {
            int u = u2 + (hf << 6);
#pragma unroll
            for (int p = 0; p < 8; ++p) {
                float v = acc[hf][p];
                int idx = u * 36 + p0 + p;
                if (st == 1 || st == 3) {
                    float hh = H[idx] + v;
                    H[idx] = hh;
                    if (st == 1) R[idx] = fmaxf(hh, 0.f);
                } else {
                    R[idx] = fmaxf(v, 0.f);
                }
            }
        }
        __syncthreads();
    }

    // projection: p1[o] = Wf[23+o] . H + bf[23+o], o in [0,23)
    if (u2 < 23) {
        const float* W = Wfg + (L * 46 + 23 + u2) * 128;
        float bias = bfg[L * 46 + 23 + u2];
        float acc[8];
#pragma unroll
        for (int p = 0; p < 8; ++p) acc[p] = 0.f;
        for (int k4 = 0; k4 < 32; ++k4) {
            float4 wA = *(const float4*)(W + (k4 << 2));
            float wa4[4] = {wA.x, wA.y, wA.z, wA.w};
#pragma unroll
            for (int kk = 0; kk < 4; ++kk) {
                const float* hh = &H[((k4 << 2) + kk) * 36 + p0];
                float4 h0 = *(const float4*)hh;
                float4 h1 = *(const float4*)(hh + 4);
                float wa = wa4[kk];
                acc[0] = fmaf(wa, h0.x, acc[0]);
                acc[1] = fmaf(wa, h0.y, acc[1]);
                acc[2] = fmaf(wa, h0.z, acc[2]);
                acc[3] = fmaf(wa, h0.w, acc[3]);
                acc[4] = fmaf(wa, h1.x, acc[4]);
                acc[5] = fmaf(wa, h1.y, acc[5]);
                acc[6] = fmaf(wa, h1.z, acc[6]);
                acc[7] = fmaf(wa, h1.w, acc[7]);
            }
        }
#pragma unroll
        for (int p = 0; p < 8; ++p)
            tab[(L * NPT + pb + p0 + p) * TROW + u2] = acc[p] + bias;
    }
}

// ------------- kernel 3: per-sample flow using the tables -------------
extern "C" __global__
void nsf_main(const float* __restrict__ z0g, const float* __restrict__ xg,
              const float* __restrict__ sgg,
              const float* __restrict__ n1w1, const float* __restrict__ n1b1,
              const float* __restrict__ n1w2, const float* __restrict__ n1b2,
              const float* __restrict__ n2w1, const float* __restrict__ n2b1,
              const float* __restrict__ n2w2, const float* __restrict__ n2b2,
              const char* __restrict__ ws, float* __restrict__ outg)
{
    __shared__ float recs_s[16 * 40];
    __shared__ float bpl[NPT];

    const float* bpg  = (const float*)(ws + BP_OFF);
    const float* tab  = (const float*)(ws + TAB_OFF);
    const float* recg = (const float*)(ws + REC_OFF);

    const int tid = threadIdx.x;
    const int s = blockIdx.x * 256 + tid;

    for (int i = tid; i < 640; i += 256) recs_s[i] = recg[i];

    // conditioning MLPs (per sample)
    float zz0, zz1, ld = 0.f;
    {
        float za = z0g[2 * s], zb = z0g[2 * s + 1];
        float xa = xg[2 * s],  xb = xg[2 * s + 1];
        float sg = sgg[s];
        float t0 = n1b2[0], t1 = n1b2[1];
#pragma unroll
        for (int m = 0; m < 32; ++m) {
            float hm = fmaf(sg, n1w1[m], n1b1[m]);
            hm = hm / (1.f + __expf(-hm));
            t0 = fmaf(hm, n1w2[m], t0);
            t1 = fmaf(hm, n1w2[32 + m], t1);
        }
        float u0 = n2b2[0], u1 = n2b2[1];
#pragma unroll
        for (int m = 0; m < 32; ++m) {
            float hm = za * n2w1[4 * m] + zb * n2w1[4 * m + 1]
                     + xa * n2w1[4 * m + 2] + xb * n2w1[4 * m + 3] + n2b1[m];
            hm = hm / (1.f + __expf(-hm));
            u0 = fmaf(hm, n2w2[m], u0);
            u1 = fmaf(hm, n2w2[32 + m], u1);
        }
        zz0 = u0 + t0; zz1 = u1 + t1;
    }

    for (int L = 0; L < 16; ++L) {
        __syncthreads();   // prev layer's bpl reads done
        {
            const float4* src = (const float4*)(bpg + L * NPT);
            float4* dst = (float4*)bpl;
            for (int i = tid; i < NPT / 4; i += 256) dst[i] = src[i];
        }
        __syncthreads();

        const float* rec = recs_s + L * 40;
        float out0, ldp0;
        rqs_knots(zz0, rec, out0, ldp0);

        // locate segment of s = out0
        int pos = 0;
#pragma unroll
        for (int st = 1024; st > 0; st >>= 1) {
            int np = pos + st;
            if (np <= NPT - 2 && bpl[np] <= out0) pos = np;
        }
        float e0 = bpl[pos], e1 = bpl[pos + 1];
        float de = e1 - e0;
        float t = (de > 1e-9f) ? (out0 - e0) / de : 0.f;

        // interpolate the 23 dim-1 spline params
        float pp[24];
        {
            const float4* r0 = (const float4*)(tab + (L * NPT + pos) * TROW);
            const float4* r1 = (const float4*)(tab + (L * NPT + pos + 1) * TROW);
#pragma unroll
            for (int i = 0; i < 6; ++i) {
                float4 a = r0[i], b = r1[i];
                pp[4 * i]     = fmaf(t, b.x - a.x, a.x);
                pp[4 * i + 1] = fmaf(t, b.y - a.y, a.y);
                pp[4 * i + 2] = fmaf(t, b.z - a.z, a.z);
                pp[4 * i + 3] = fmaf(t, b.w - a.w, a.w);
            }
        }

        float out1, ldp1;
        rqs_inv(zz1, pp, out1, ldp1);
        ld += ldp0 + ldp1;

        float v0 = out0 - rec[31], v1 = out1 - rec[32];
        zz0 = fmaf(v0, rec[27], v1 * rec[28]);
        zz1 = fmaf(v0, rec[29], v1 * rec[30]);
    }

    float ldc = *(const float*)(ws + LDC_OFF);
    outg[2 * s] = zz0;
    outg[2 * s + 1] = zz1;
    outg[2 * NBATCH + s] = ld - ldc;
}

extern "C" void kernel_launch(void* const* d_in, const int* in_sizes, int n_in,
                              void* d_out, int out_size, void* d_ws, size_t ws_size,
                              hipStream_t stream)
{
    const float* z0g  = (const float*)d_in[0];
    const float* xg   = (const float*)d_in[1];
    const float* sgg  = (const float*)d_in[2];
    const float* n1w1 = (const float*)d_in[3];
    const float* n1b1 = (const float*)d_in[4];
    const float* n1w2 = (const float*)d_in[5];
    const float* n1b2 = (const float*)d_in[6];
    const float* n2w1 = (const float*)d_in[7];
    const float* n2b1 = (const float*)d_in[8];
    const float* n2w2 = (const float*)d_in[9];
    const float* n2b2 = (const float*)d_in[10];
    const float* W0g  = (const float*)d_in[11];
    const float* b0g  = (const float*)d_in[12];
    const float* Wres = (const float*)d_in[13];
    const float* bres = (const float*)d_in[14];
    const float* Wfg  = (const float*)d_in[15];
    const float* bfg  = (const float*)d_in[16];
    const float* lul  = (const float*)d_in[17];
    const float* luu  = (const float*)d_in[18];
    const float* lud  = (const float*)d_in[19];
    const float* lub  = (const float*)d_in[20];
    const int*   perms= (const int*)d_in[21];
    float* outg = (float*)d_out;
    char* ws = (char*)d_ws;

    nsf_sort<<<16, 256, 0, stream>>>(W0g, b0g, bfg, lul, luu, lud, lub, perms, ws);
    nsf_eval<<<1024, 256, 0, stream>>>(Wres, bres, Wfg, bfg, W0g, b0g, ws);
    nsf_main<<<NBATCH / 256, 256, 0, stream>>>(z0g, xg, sgg,
                                               n1w1, n1b1, n1w2, n1b2,
                                               n2w1, n2b1, n2w2, n2b2,
                                               ws, outg);
}

// Round 8
// 322.035 us; speedup vs baseline: 5.1113x; 1.3291x over previous
//
#include <hip/hip_runtime.h>
#include <math.h>

#define NBATCH 262144
#define INVSQH 0.08838834764831845f   // 1/sqrt(128)

#define NPT   2048
#define NGRID 1920
#define TROW  24

// ---- workspace layout (bytes), total ~7.76 MB ----
#define WT_OFF   0          // Wres transposed [sidx][k][u] f32: 4,194,304
#define WFT_OFF  4194304    // WfT [L][k][32] f32 (o>=23 zero): 262,144
#define WS0_OFF  4456448    // W0 col0 [L][128] f32: 8,192
#define XS_OFF   4464640    // sorted crossings [L][128] f32: 8,192
#define BP_OFF   4472832    // merged breakpoints [L][2048] f32: 131,072
#define TAB_OFF  4603904    // table [L][2048][24] f32 (col 23 = breakpoint): 3,145,728
#define REC_OFF  7749632    // 16*40 f32
#define LDC_OFF  7752192    // 1 f32

__device__ __forceinline__ float softplusf(float x) {
    return (x > 15.f) ? x : __logf(1.f + __expf(x));
}

// implicit sorted grid: low coarse(192) | dense(1408) | high coarse(192) | pad(128)
__device__ __forceinline__ float gridval(int i) {
    float v = -56.8f + i * 0.25f;
    if (i >= 192)  v = -8.8f + (i - 192) * 0.0125f;
    if (i >= 1600) v = 9.05f + (i - 1600) * 0.25f;
    if (i >= 1792) v = 58.5f + (i - 1792) * 0.01f;
    return v;
}
// count of grid values <= x (exact: compares against gridval itself)
__device__ __forceinline__ int cnt_grid_le(float x) {
    int c = 0;
#pragma unroll
    for (int stp = 1024; stp; stp >>= 1) {
        int n = c + stp;
        if (n <= NGRID && gridval(n - 1) <= x) c = n;
    }
    return c;
}

__device__ __forceinline__ void rqs_solve(float y, float yc, float yk, float hk, float xk,
                                          float wk, float dk, float dk1,
                                          float& xout, float& ldout)
{
    float sk = hk / wk;
    float dy = yc - yk;
    float t2 = dk + dk1 - 2.f * sk;
    float av = dy * t2 + hk * (sk - dk);
    float bv = hk * dk - dy * t2;
    float cv = -sk * dy;
    float disc = fmaxf(bv * bv - 4.f * av * cv, 0.f);
    float theta = 2.f * cv / (-bv - sqrtf(disc));
    float xo = fmaf(theta, wk, xk);
    float om = 1.f - theta;
    float denom = fmaf(t2, theta * om, sk);
    float dnum = sk * sk * (dk1 * theta * theta + 2.f * sk * theta * om + dk * om * om);
    float ldf = __logf(dnum) - 2.f * __logf(denom);
    bool inside = (y >= -3.f) && (y <= 3.f);
    xout  = inside ? xo : y;
    ldout = inside ? -ldf : 0.f;
}

__device__ __forceinline__ void rqs_inv(float y, const float* __restrict__ p,
                                        float& xout, float& ldout)
{
    float uw[8], uh[8];
#pragma unroll
    for (int j = 0; j < 8; ++j) uw[j] = p[j] * INVSQH;
#pragma unroll
    for (int j = 0; j < 8; ++j) uh[j] = p[8 + j] * INVSQH;
    float mw = uw[0], mh = uh[0];
#pragma unroll
    for (int j = 1; j < 8; ++j) { mw = fmaxf(mw, uw[j]); mh = fmaxf(mh, uh[j]); }
    float ew[8], eh[8], sw = 0.f, sh = 0.f;
#pragma unroll
    for (int j = 0; j < 8; ++j) {
        ew[j] = __expf(uw[j] - mw); sw += ew[j];
        eh[j] = __expf(uh[j] - mh); sh += eh[j];
    }
    float isw = 0.992f / sw, ish = 0.992f / sh;
    float cw[9], ch[9];
    cw[0] = -3.f; ch[0] = -3.f;
    float aw = 0.f, ah = 0.f;
#pragma unroll
    for (int j = 0; j < 8; ++j) {
        aw += 0.001f + ew[j] * isw;
        ah += 0.001f + eh[j] * ish;
        cw[j + 1] = 6.f * aw - 3.f;
        ch[j + 1] = 6.f * ah - 3.f;
    }
    cw[8] = 3.f; ch[8] = 3.f;
    float d[9];
    d[0] = 1.f; d[8] = 1.f;
#pragma unroll
    for (int j = 0; j < 7; ++j) d[j + 1] = 0.001f + softplusf(p[16 + j]);

    float yc = fminf(fmaxf(y, -3.f), 3.f);
    float yk = ch[0], hk = ch[1] - ch[0], xk = cw[0], wk = cw[1] - cw[0];
    float dk = d[0], dk1 = d[1];
#pragma unroll
    for (int j = 1; j < 8; ++j) {
        bool cge = (yc >= ch[j]);
        yk  = cge ? ch[j] : yk;
        hk  = cge ? (ch[j + 1] - ch[j]) : hk;
        xk  = cge ? cw[j] : xk;
        wk  = cge ? (cw[j + 1] - cw[j]) : wk;
        dk  = cge ? d[j] : dk;
        dk1 = cge ? d[j + 1] : dk1;
    }
    rqs_solve(y, yc, yk, hk, xk, wk, dk, dk1, xout, ldout);
}

__device__ __forceinline__ void rqs_knots(float y, const float* __restrict__ rec,
                                          float& xout, float& ldout)
{
    const float* cw = rec;
    const float* ch = rec + 9;
    const float* dd = rec + 18;
    float yc = fminf(fmaxf(y, -3.f), 3.f);
    float yk = ch[0], hk = ch[1] - ch[0], xk = cw[0], wk = cw[1] - cw[0];
    float dk = dd[0], dk1 = dd[1];
#pragma unroll
    for (int j = 1; j < 8; ++j) {
        bool cge = (yc >= ch[j]);
        yk  = cge ? ch[j] : yk;
        hk  = cge ? (ch[j + 1] - ch[j]) : hk;
        xk  = cge ? cw[j] : xk;
        wk  = cge ? (cw[j + 1] - cw[j]) : wk;
        dk  = cge ? dd[j] : dk;
        dk1 = cge ? dd[j + 1] : dk1;
    }
    rqs_solve(y, yc, yk, hk, xk, wk, dk, dk1, xout, ldout);
}

// ------------- kernel 1: weight images + crossing sort + merged breakpoints + rec -------------
extern "C" __global__ __launch_bounds__(256)
void nsf_prep(const float* __restrict__ Wresg, const float* __restrict__ Wfg,
              const float* __restrict__ W0g,  const float* __restrict__ b0g,
              const float* __restrict__ bfg,
              const float* __restrict__ lulg, const float* __restrict__ luug,
              const float* __restrict__ ludg, const float* __restrict__ lubg,
              const int* __restrict__ permsg, char* __restrict__ ws)
{
    const int t = blockIdx.x * 256 + threadIdx.x;
    const int stride = gridDim.x * 256;
    float* WT  = (float*)(ws + WT_OFF);
    float* WFT = (float*)(ws + WFT_OFF);
    float* ws0 = (float*)(ws + WS0_OFF);
    float* xsg = (float*)(ws + XS_OFF);
    float* bp  = (float*)(ws + BP_OFF);

    // Wres transpose: WT[sidx][k][u] = Wres[sidx][u][k]
    for (int e = t; e < 16 * 4 * 16384; e += stride) {
        int sidx = e >> 14, rem = e & 16383, k = rem >> 7, u = rem & 127;
        WT[e] = Wresg[sidx * 16384 + u * 128 + k];
    }
    // WfT padded to 32 outputs
    for (int e = t; e < 16 * 128 * 32; e += stride) {
        int L = e >> 12, rem = e & 4095, k = rem >> 5, o = rem & 31;
        WFT[e] = (o < 23) ? Wfg[(L * 46 + 23 + o) * 128 + k] : 0.f;
    }
    for (int e = t; e < 2048; e += stride) ws0[e] = W0g[2 * e];

    if (blockIdx.x < 16) {
        __shared__ float xr[128], xsL[128];
        const int L = blockIdx.x, tid = threadIdx.x;
        if (tid < 128) {
            float aa = W0g[L * 256 + 2 * tid];
            float cc = b0g[L * 128 + tid];
            float xv = -cc / aa;
            xr[tid] = (fabsf(xv) < 56.0f) ? xv : (57.0f + tid * 0.01f);
        }
        __syncthreads();
        if (tid < 128) {      // rank sort, index tie-break
            float v = xr[tid];
            int rank = 0;
            for (int j = 0; j < 128; ++j) {
                float u = xr[j];
                rank += (u < v || (u == v && j < tid)) ? 1 : 0;
            }
            xsL[rank] = v;
        }
        __syncthreads();
        if (tid < 128) {
            float v = xsL[tid];
            xsg[L * 128 + tid] = v;
            bp[L * NPT + tid + cnt_grid_le(v)] = v;    // crossings after equal grid pts
        }
        // grid elements: rank = i + #crossings strictly below
        for (int i = tid; i < NGRID; i += 256) {
            float g = gridval(i);
            int cl = 0;
#pragma unroll
            for (int stp = 64; stp; stp >>= 1)
                if (xsL[cl + stp - 1] < g) cl += stp;
            bp[L * NPT + i + cl] = g;
        }
        if (tid == 0) {
            float* rec = (float*)(ws + REC_OFF) + L * 40;
            const float* p = bfg + L * 46;
            for (int half = 0; half < 2; ++half) {
                float u[8], m = -1e30f;
                for (int j = 0; j < 8; ++j) { u[j] = p[half * 8 + j] * INVSQH; m = fmaxf(m, u[j]); }
                float e[8], ssum = 0.f;
                for (int j = 0; j < 8; ++j) { e[j] = expf(u[j] - m); ssum += e[j]; }
                float cum = 0.f;
                rec[half * 9 + 0] = -3.f;
                for (int j = 0; j < 8; ++j) {
                    cum += 0.001f + 0.992f * e[j] / ssum;
                    rec[half * 9 + 1 + j] = 6.f * cum - 3.f;
                }
                rec[half * 9 + 8] = 3.f;
            }
            rec[18] = 1.f; rec[26] = 1.f;
            for (int j = 0; j < 7; ++j) {
                float x = p[16 + j];
                rec[19 + j] = 0.001f + ((x > 15.f) ? x : log1pf(expf(x)));
            }
            float x0 = ludg[2 * L], x1 = ludg[2 * L + 1];
            float dg0 = 0.001f + ((x0 > 15.f) ? x0 : log1pf(expf(x0)));
            float dg1 = 0.001f + ((x1 > 15.f) ? x1 : log1pf(expf(x1)));
            float ll = lulg[L], uu = luug[L];
            float det = dg0 * dg1;
            float c00 = (ll * uu + dg1) / det, c01 = -uu / det;
            float c10 = -ll / dg1, c11 = 1.f / dg1;
            int pa = permsg[2 * L], pb = permsg[2 * L + 1];
            rec[27] = pa ? c10 : c00; rec[28] = pa ? c11 : c01;
            rec[29] = pb ? c10 : c00; rec[30] = pb ? c11 : c01;
            rec[31] = lubg[2 * L];    rec[32] = lubg[2 * L + 1];
        }
        if (L == 0 && tid == 32) {
            float ssum = 0.f;
            for (int l2 = 0; l2 < 16; ++l2) {
                float x0 = ludg[2 * l2], x1 = ludg[2 * l2 + 1];
                float dg0 = 0.001f + ((x0 > 15.f) ? x0 : log1pf(expf(x0)));
                float dg1 = 0.001f + ((x1 > 15.f) ? x1 : log1pf(expf(x1)));
                ssum += logf(dg0) + logf(dg1);
            }
            *(float*)(ws + LDC_OFF) = ssum;
        }
    }
}

// ------------- kernel 2: table evaluation, VALU-bound, wave-private, barrier-free -------------
// 512 blocks = 16 layers x 32 chunks of 64 points. Thread (og=tid&15, pg=tid>>4):
// outputs u0=og*8..+7, points pg*4..+3. H (residual) in registers. R in LDS [k][pt].
extern "C" __global__ __launch_bounds__(256, 2)
void nsf_eval(const float* __restrict__ bresg, const float* __restrict__ b0g,
              const float* __restrict__ bfg, char* __restrict__ ws)
{
    __shared__ float R[128 * 68];          // row stride 68 floats (16B-aligned rows)
    const int tid = threadIdx.x;
    const int og = tid & 15, pg = tid >> 4;
    const int u0 = og * 8;
    const int L = blockIdx.x >> 5;
    const int pb = (blockIdx.x & 31) << 6;

    const float* WT  = (const float*)(ws + WT_OFF);
    const float* WFT = (const float*)(ws + WFT_OFF);
    const float* ws0 = (const float*)(ws + WS0_OFF);
    const float* bp  = (const float*)(ws + BP_OFF);
    float* tab = (float*)(ws + TAB_OFF);

    float H[8][4];
    {
        float4 s4 = *(const float4*)(bp + L * NPT + pb + pg * 4);
        float sp[4] = {s4.x, s4.y, s4.z, s4.w};
        float4 a0 = *(const float4*)(ws0 + L * 128 + u0);
        float4 a1 = *(const float4*)(ws0 + L * 128 + u0 + 4);
        float4 c0 = *(const float4*)(b0g + L * 128 + u0);
        float4 c1 = *(const float4*)(b0g + L * 128 + u0 + 4);
        float aj[8] = {a0.x, a0.y, a0.z, a0.w, a1.x, a1.y, a1.z, a1.w};
        float cj[8] = {c0.x, c0.y, c0.z, c0.w, c1.x, c1.y, c1.z, c1.w};
#pragma unroll
        for (int j = 0; j < 8; ++j) {
#pragma unroll
            for (int p = 0; p < 4; ++p) H[j][p] = fmaf(aj[j], sp[p], cj[j]);
            float4 v = {fmaxf(H[j][0], 0.f), fmaxf(H[j][1], 0.f),
                        fmaxf(H[j][2], 0.f), fmaxf(H[j][3], 0.f)};
            *(float4*)(&R[(u0 + j) * 68 + pg * 4]) = v;
        }
    }
    __threadfence_block();   // R is wave-private (points partitioned by wave): fence, no barrier

#pragma unroll 1
    for (int st = 0; st < 4; ++st) {
        const float* Wst = WT + (L * 4 + st) * 16384;
        const float* bb  = bresg + (L * 4 + st) * 128;
        float acc[8][4];
        {
            float4 b0v = *(const float4*)(bb + u0);
            float4 b1v = *(const float4*)(bb + u0 + 4);
            float bj[8] = {b0v.x, b0v.y, b0v.z, b0v.w, b1v.x, b1v.y, b1v.z, b1v.w};
#pragma unroll
            for (int j = 0; j < 8; ++j)
#pragma unroll
                for (int p = 0; p < 4; ++p) acc[j][p] = bj[j];
        }
#pragma unroll 4
        for (int k = 0; k < 128; ++k) {
            float4 w0 = *(const float4*)(Wst + k * 128 + u0);      // coalesced, L1-shared
            float4 w1 = *(const float4*)(Wst + k * 128 + u0 + 4);
            float4 r  = *(const float4*)(&R[k * 68 + pg * 4]);     // 4-address gather
            float wj[8] = {w0.x, w0.y, w0.z, w0.w, w1.x, w1.y, w1.z, w1.w};
            float rp[4] = {r.x, r.y, r.z, r.w};
#pragma unroll
            for (int j = 0; j < 8; ++j)
#pragma unroll
                for (int p = 0; p < 4; ++p)
                    acc[j][p] = fmaf(wj[j], rp[p], acc[j][p]);
        }
        if (st == 1 || st == 3) {
#pragma unroll
            for (int j = 0; j < 8; ++j)
#pragma unroll
                for (int p = 0; p < 4; ++p) H[j][p] += acc[j][p];
        }
#pragma unroll
        for (int j = 0; j < 8; ++j) {
            float4 v;
            if (st == 0 || st == 2) {
                v = (float4){fmaxf(acc[j][0], 0.f), fmaxf(acc[j][1], 0.f),
                             fmaxf(acc[j][2], 0.f), fmaxf(acc[j][3], 0.f)};
            } else if (st == 1) {
                v = (float4){fmaxf(H[j][0], 0.f), fmaxf(H[j][1], 0.f),
                             fmaxf(H[j][2], 0.f), fmaxf(H[j][3], 0.f)};
            } else {  // st == 3: raw H for the projection
                v = (float4){H[j][0], H[j][1], H[j][2], H[j][3]};
            }
            *(float4*)(&R[(u0 + j) * 68 + pg * 4]) = v;
        }
        __threadfence_block();
    }

    // projection: thread (o=tid&31, pg8=tid>>5) -> 8 points; col 23 stores breakpoint value
    {
        const int o = tid & 31, pg8 = tid >> 5;
        float pacc[8];
#pragma unroll
        for (int p = 0; p < 8; ++p) pacc[p] = 0.f;
#pragma unroll 4
        for (int k = 0; k < 128; ++k) {
            float wf = WFT[(L * 128 + k) * 32 + o];
            float4 ra = *(const float4*)(&R[k * 68 + pg8 * 8]);
            float4 rb = *(const float4*)(&R[k * 68 + pg8 * 8 + 4]);
            pacc[0] = fmaf(wf, ra.x, pacc[0]);
            pacc[1] = fmaf(wf, ra.y, pacc[1]);
            pacc[2] = fmaf(wf, ra.z, pacc[2]);
            pacc[3] = fmaf(wf, ra.w, pacc[3]);
            pacc[4] = fmaf(wf, rb.x, pacc[4]);
            pacc[5] = fmaf(wf, rb.y, pacc[5]);
            pacc[6] = fmaf(wf, rb.z, pacc[6]);
            pacc[7] = fmaf(wf, rb.w, pacc[7]);
        }
        const int rowb = (L * NPT + pb + pg8 * 8) * TROW;
        if (o < 23) {
            float bias = bfg[L * 46 + 23 + o];
#pragma unroll
            for (int p = 0; p < 8; ++p)
                tab[rowb + p * TROW + o] = pacc[p] + bias;
        } else if (o == 23) {
            float4 sa = *(const float4*)(bp + L * NPT + pb + pg8 * 8);
            float4 sb = *(const float4*)(bp + L * NPT + pb + pg8 * 8 + 4);
            float sv[8] = {sa.x, sa.y, sa.z, sa.w, sb.x, sb.y, sb.z, sb.w};
#pragma unroll
            for (int p = 0; p < 8; ++p)
                tab[rowb + p * TROW + 23] = sv[p];
        }
    }
}

// ------------- kernel 3: per-sample flow; locate via implicit grid + crossing search -------------
extern "C" __global__ __launch_bounds__(256)
void nsf_main(const float* __restrict__ z0g, const float* __restrict__ xg,
              const float* __restrict__ sgg,
              const float* __restrict__ n1w1, const float* __restrict__ n1b1,
              const float* __restrict__ n1w2, const float* __restrict__ n1b2,
              const float* __restrict__ n2w1, const float* __restrict__ n2b1,
              const float* __restrict__ n2w2, const float* __restrict__ n2b2,
              const char* __restrict__ ws, float* __restrict__ outg)
{
    __shared__ float xsl[16 * 128];
    __shared__ float recs_s[16 * 40];

    const float* xsg  = (const float*)(ws + XS_OFF);
    const float* tab  = (const float*)(ws + TAB_OFF);
    const float* recg = (const float*)(ws + REC_OFF);

    const int tid = threadIdx.x;
    const int s = blockIdx.x * 256 + tid;

    for (int i = tid; i < 2048; i += 256) xsl[i] = xsg[i];
    for (int i = tid; i < 640; i += 256) recs_s[i] = recg[i];
    __syncthreads();

    float zz0, zz1, ld = 0.f;
    {
        float za = z0g[2 * s], zb = z0g[2 * s + 1];
        float xa = xg[2 * s],  xb = xg[2 * s + 1];
        float sg = sgg[s];
        float t0 = n1b2[0], t1 = n1b2[1];
#pragma unroll
        for (int m = 0; m < 32; ++m) {
            float hm = fmaf(sg, n1w1[m], n1b1[m]);
            hm = hm / (1.f + __expf(-hm));
            t0 = fmaf(hm, n1w2[m], t0);
            t1 = fmaf(hm, n1w2[32 + m], t1);
        }
        float u0 = n2b2[0], u1 = n2b2[1];
#pragma unroll
        for (int m = 0; m < 32; ++m) {
            float hm = za * n2w1[4 * m] + zb * n2w1[4 * m + 1]
                     + xa * n2w1[4 * m + 2] + xb * n2w1[4 * m + 3] + n2b1[m];
            hm = hm / (1.f + __expf(-hm));
            u0 = fmaf(hm, n2w2[m], u0);
            u1 = fmaf(hm, n2w2[32 + m], u1);
        }
        zz0 = u0 + t0; zz1 = u1 + t1;
    }

    for (int L = 0; L < 16; ++L) {
        const float* rec = recs_s + L * 40;
        float out0, ldp0;
        rqs_knots(zz0, rec, out0, ldp0);

        // segment index = #elements <= out0, minus 1 (grid closed-form + crossing search)
        int cg = cnt_grid_le(out0);
        const float* xs = xsl + L * 128;
        int cx = 0;
#pragma unroll
        for (int stp = 64; stp; stp >>= 1)
            if (xs[cx + stp - 1] <= out0) cx += stp;
        int pos = cg + cx - 1;
        pos = max(0, min(pos, NPT - 2));

        const float4* r0 = (const float4*)(tab + (L * NPT + pos) * TROW);
        float4 q0[6], q1[6];
#pragma unroll
        for (int i = 0; i < 6; ++i) { q0[i] = r0[i]; q1[i] = r0[i + 6]; }
        float e0 = q0[5].w, e1 = q1[5].w;        // breakpoint values live in col 23
        float de = e1 - e0;
        float tt = (de > 1e-9f) ? (out0 - e0) / de : 0.f;

        float pp[24];
#pragma unroll
        for (int i = 0; i < 6; ++i) {
            pp[4 * i]     = fmaf(tt, q1[i].x - q0[i].x, q0[i].x);
            pp[4 * i + 1] = fmaf(tt, q1[i].y - q0[i].y, q0[i].y);
            pp[4 * i + 2] = fmaf(tt, q1[i].z - q0[i].z, q0[i].z);
            pp[4 * i + 3] = fmaf(tt, q1[i].w - q0[i].w, q0[i].w);
        }

        float out1, ldp1;
        rqs_inv(zz1, pp, out1, ldp1);
        ld += ldp0 + ldp1;

        float v0 = out0 - rec[31], v1 = out1 - rec[32];
        zz0 = fmaf(v0, rec[27], v1 * rec[28]);
        zz1 = fmaf(v0, rec[29], v1 * rec[30]);
    }

    float ldc = *(const float*)(ws + LDC_OFF);
    outg[2 * s] = zz0;
    outg[2 * s + 1] = zz1;
    outg[2 * NBATCH + s] = ld - ldc;
}

extern "C" void kernel_launch(void* const* d_in, const int* in_sizes, int n_in,
                              void* d_out, int out_size, void* d_ws, size_t ws_size,
                              hipStream_t stream)
{
    const float* z0g  = (const float*)d_in[0];
    const float* xg   = (const float*)d_in[1];
    const float* sgg  = (const float*)d_in[2];
    const float* n1w1 = (const float*)d_in[3];
    const float* n1b1 = (const float*)d_in[4];
    const float* n1w2 = (const float*)d_in[5];
    const float* n1b2 = (const float*)d_in[6];
    const float* n2w1 = (const float*)d_in[7];
    const float* n2b1 = (const float*)d_in[8];
    const float* n2w2 = (const float*)d_in[9];
    const float* n2b2 = (const float*)d_in[10];
    const float* W0g  = (const float*)d_in[11];
    const float* b0g  = (const float*)d_in[12];
    const float* Wres = (const float*)d_in[13];
    const float* bres = (const float*)d_in[14];
    const float* Wfg  = (const float*)d_in[15];
    const float* bfg  = (const float*)d_in[16];
    const float* lul  = (const float*)d_in[17];
    const float* luu  = (const float*)d_in[18];
    const float* lud  = (const float*)d_in[19];
    const float* lub  = (const float*)d_in[20];
    const int*   perms= (const int*)d_in[21];
    float* outg = (float*)d_out;
    char* ws = (char*)d_ws;

    nsf_prep<<<256, 256, 0, stream>>>(Wres, Wfg, W0g, b0g, bfg, lul, luu, lud, lub, perms, ws);
    nsf_eval<<<512, 256, 0, stream>>>(bres, b0g, bfg, ws);
    nsf_main<<<NBATCH / 256, 256, 0, stream>>>(z0g, xg, sgg,
                                               n1w1, n1b1, n1w2, n1b2,
                                               n2w1, n2b1, n2w2, n2b2,
                                               ws, outg);
}

// Round 9
// 284.812 us; speedup vs baseline: 5.7793x; 1.1307x over previous
//
#include <hip/hip_runtime.h>
#include <math.h>

#define NBATCH 262144
#define INVSQH 0.08838834764831845f   // 1/sqrt(128)

#define NPT   2048
#define NGRID 1920
#define TROW  24

// ---- workspace layout (bytes), total ~7.76 MB ----
#define WT_OFF   0          // Wres transposed [sidx][k][u] f32: 4,194,304
#define WFT_OFF  4194304    // WfT [L][k][32] f32 (o>=23 zero): 262,144
#define WS0_OFF  4456448    // W0 col0 [L][128] f32: 8,192
#define XS_OFF   4464640    // sorted crossings [L][128] f32: 8,192
#define BP_OFF   4472832    // merged breakpoints [L][2048] f32: 131,072
#define TAB_OFF  4603904    // knot table [L][2048][24] f32: cw1..8|ch1..8|d1..7|bp
#define REC_OFF  7749632    // 16*40 f32
#define LDC_OFF  7752192    // 1 f32

__device__ __forceinline__ float softplusf(float x) {
    return (x > 15.f) ? x : __logf(1.f + __expf(x));
}

// implicit sorted grid: low coarse(192) | dense(1408) | high coarse(192) | pad(128)
__device__ __forceinline__ float gridval(int i) {
    float v = -56.8f + i * 0.25f;
    if (i >= 192)  v = -8.8f + (i - 192) * 0.0125f;
    if (i >= 1600) v = 9.05f + (i - 1600) * 0.25f;
    if (i >= 1792) v = 58.5f + (i - 1792) * 0.01f;
    return v;
}
// exact (binary-search) count, used only in prep where exactness vs gridval matters
__device__ __forceinline__ int cnt_grid_le_exact(float x) {
    int c = 0;
#pragma unroll
    for (int stp = 1024; stp; stp >>= 1) {
        int n = c + stp;
        if (n <= NGRID && gridval(n - 1) <= x) c = n;
    }
    return c;
}
// closed-form count for main: piecewise-uniform grid. Off-by-one from float
// rounding is benign (t computed from stored endpoints -> sub-cell extrapolation).
__device__ __forceinline__ int cnt_grid_le_fast(float x) {
    if (x < -56.8f) return 0;
    if (x < -8.8f)  return min((int)floorf((x + 56.8f) * 4.0f) + 1, 192);
    if (x < 9.05f)  return 192 + min((int)floorf((x + 8.8f) * 80.0f) + 1, 1408);
    if (x < 58.5f)  return 1600 + min((int)floorf((x - 9.05f) * 4.0f) + 1, 192);
    return 1792 + min((int)floorf((x - 58.5f) * 100.0f) + 1, 128);
}

__device__ __forceinline__ void rqs_solve(float y, float yc, float yk, float hk, float xk,
                                          float wk, float dk, float dk1,
                                          float& xout, float& ldout)
{
    float sk = hk / wk;
    float dy = yc - yk;
    float t2 = dk + dk1 - 2.f * sk;
    float av = dy * t2 + hk * (sk - dk);
    float bv = hk * dk - dy * t2;
    float cv = -sk * dy;
    float disc = fmaxf(bv * bv - 4.f * av * cv, 0.f);
    float theta = 2.f * cv / (-bv - sqrtf(disc));
    float xo = fmaf(theta, wk, xk);
    float om = 1.f - theta;
    float denom = fmaf(t2, theta * om, sk);
    float dnum = sk * sk * (dk1 * theta * theta + 2.f * sk * theta * om + dk * om * om);
    float ldf = __logf(dnum) - 2.f * __logf(denom);
    bool inside = (y >= -3.f) && (y <= 3.f);
    xout  = inside ? xo : y;
    ldout = inside ? -ldf : 0.f;
}

// knots from raw params p[0..22] (used in eval's knot phase; mirrors reference math)
__device__ __forceinline__ void knots_from_p(const float* __restrict__ p,
                                             float* __restrict__ cw,
                                             float* __restrict__ ch,
                                             float* __restrict__ d)
{
    float uw[8], uh[8];
#pragma unroll
    for (int j = 0; j < 8; ++j) uw[j] = p[j] * INVSQH;
#pragma unroll
    for (int j = 0; j < 8; ++j) uh[j] = p[8 + j] * INVSQH;
    float mw = uw[0], mh = uh[0];
#pragma unroll
    for (int j = 1; j < 8; ++j) { mw = fmaxf(mw, uw[j]); mh = fmaxf(mh, uh[j]); }
    float ew[8], eh[8], sw = 0.f, sh = 0.f;
#pragma unroll
    for (int j = 0; j < 8; ++j) {
        ew[j] = __expf(uw[j] - mw); sw += ew[j];
        eh[j] = __expf(uh[j] - mh); sh += eh[j];
    }
    float isw = 0.992f / sw, ish = 0.992f / sh;
    cw[0] = -3.f; ch[0] = -3.f;
    float aw = 0.f, ah = 0.f;
#pragma unroll
    for (int j = 0; j < 8; ++j) {
        aw += 0.001f + ew[j] * isw;
        ah += 0.001f + eh[j] * ish;
        cw[j + 1] = 6.f * aw - 3.f;
        ch[j + 1] = 6.f * ah - 3.f;
    }
    cw[8] = 3.f; ch[8] = 3.f;
    d[0] = 1.f; d[8] = 1.f;
#pragma unroll
    for (int j = 0; j < 7; ++j) d[j + 1] = 0.001f + softplusf(p[16 + j]);
}

// RQS inverse from knot arrays
__device__ __forceinline__ void rqs_from_knots(float y, const float* __restrict__ cw,
                                               const float* __restrict__ ch,
                                               const float* __restrict__ d,
                                               float& xout, float& ldout)
{
    float yc = fminf(fmaxf(y, -3.f), 3.f);
    float yk = ch[0], hk = ch[1] - ch[0], xk = cw[0], wk = cw[1] - cw[0];
    float dk = d[0], dk1 = d[1];
#pragma unroll
    for (int j = 1; j < 8; ++j) {
        bool cge = (yc >= ch[j]);
        yk  = cge ? ch[j] : yk;
        hk  = cge ? (ch[j + 1] - ch[j]) : hk;
        xk  = cge ? cw[j] : xk;
        wk  = cge ? (cw[j + 1] - cw[j]) : wk;
        dk  = cge ? d[j] : dk;
        dk1 = cge ? d[j + 1] : dk1;
    }
    rqs_solve(y, yc, yk, hk, xk, wk, dk, dk1, xout, ldout);
}

// RQS inverse from precomputed rec = {cw[9], ch[9], d[9]} (dim-0)
__device__ __forceinline__ void rqs_knots(float y, const float* __restrict__ rec,
                                          float& xout, float& ldout)
{
    rqs_from_knots(y, rec, rec + 9, rec + 18, xout, ldout);
}

// ------------- kernel 1: weight images + crossing sort + merged breakpoints + rec -------------
extern "C" __global__ __launch_bounds__(256)
void nsf_prep(const float* __restrict__ Wresg, const float* __restrict__ Wfg,
              const float* __restrict__ W0g,  const float* __restrict__ b0g,
              const float* __restrict__ bfg,
              const float* __restrict__ lulg, const float* __restrict__ luug,
              const float* __restrict__ ludg, const float* __restrict__ lubg,
              const int* __restrict__ permsg, char* __restrict__ ws)
{
    const int t = blockIdx.x * 256 + threadIdx.x;
    const int stride = gridDim.x * 256;
    float* WT  = (float*)(ws + WT_OFF);
    float* WFT = (float*)(ws + WFT_OFF);
    float* ws0 = (float*)(ws + WS0_OFF);
    float* xsg = (float*)(ws + XS_OFF);
    float* bp  = (float*)(ws + BP_OFF);

    for (int e = t; e < 16 * 4 * 16384; e += stride) {
        int sidx = e >> 14, rem = e & 16383, k = rem >> 7, u = rem & 127;
        WT[e] = Wresg[sidx * 16384 + u * 128 + k];
    }
    for (int e = t; e < 16 * 128 * 32; e += stride) {
        int L = e >> 12, rem = e & 4095, k = rem >> 5, o = rem & 31;
        WFT[e] = (o < 23) ? Wfg[(L * 46 + 23 + o) * 128 + k] : 0.f;
    }
    for (int e = t; e < 2048; e += stride) ws0[e] = W0g[2 * e];

    if (blockIdx.x < 16) {
        __shared__ float xr[128], xsL[128];
        const int L = blockIdx.x, tid = threadIdx.x;
        if (tid < 128) {
            float aa = W0g[L * 256 + 2 * tid];
            float cc = b0g[L * 128 + tid];
            float xv = -cc / aa;
            xr[tid] = (fabsf(xv) < 56.0f) ? xv : (57.0f + tid * 0.01f);
        }
        __syncthreads();
        if (tid < 128) {
            float v = xr[tid];
            int rank = 0;
            for (int j = 0; j < 128; ++j) {
                float u = xr[j];
                rank += (u < v || (u == v && j < tid)) ? 1 : 0;
            }
            xsL[rank] = v;
        }
        __syncthreads();
        if (tid < 128) {
            float v = xsL[tid];
            xsg[L * 128 + tid] = v;
            bp[L * NPT + tid + cnt_grid_le_exact(v)] = v;
        }
        for (int i = tid; i < NGRID; i += 256) {
            float g = gridval(i);
            int cl = 0;
#pragma unroll
            for (int stp = 64; stp; stp >>= 1)
                if (xsL[cl + stp - 1] < g) cl += stp;
            bp[L * NPT + i + cl] = g;
        }
        if (tid == 0) {
            float* rec = (float*)(ws + REC_OFF) + L * 40;
            const float* p = bfg + L * 46;
            for (int half = 0; half < 2; ++half) {
                float u[8], m = -1e30f;
                for (int j = 0; j < 8; ++j) { u[j] = p[half * 8 + j] * INVSQH; m = fmaxf(m, u[j]); }
                float e[8], ssum = 0.f;
                for (int j = 0; j < 8; ++j) { e[j] = expf(u[j] - m); ssum += e[j]; }
                float cum = 0.f;
                rec[half * 9 + 0] = -3.f;
                for (int j = 0; j < 8; ++j) {
                    cum += 0.001f + 0.992f * e[j] / ssum;
                    rec[half * 9 + 1 + j] = 6.f * cum - 3.f;
                }
                rec[half * 9 + 8] = 3.f;
            }
            rec[18] = 1.f; rec[26] = 1.f;
            for (int j = 0; j < 7; ++j) {
                float x = p[16 + j];
                rec[19 + j] = 0.001f + ((x > 15.f) ? x : log1pf(expf(x)));
            }
            float x0 = ludg[2 * L], x1 = ludg[2 * L + 1];
            float dg0 = 0.001f + ((x0 > 15.f) ? x0 : log1pf(expf(x0)));
            float dg1 = 0.001f + ((x1 > 15.f) ? x1 : log1pf(expf(x1)));
            float ll = lulg[L], uu = luug[L];
            float det = dg0 * dg1;
            float c00 = (ll * uu + dg1) / det, c01 = -uu / det;
            float c10 = -ll / dg1, c11 = 1.f / dg1;
            int pa = permsg[2 * L], pb = permsg[2 * L + 1];
            rec[27] = pa ? c10 : c00; rec[28] = pa ? c11 : c01;
            rec[29] = pb ? c10 : c00; rec[30] = pb ? c11 : c01;
            rec[31] = lubg[2 * L];    rec[32] = lubg[2 * L + 1];
        }
        if (L == 0 && tid == 32) {
            float ssum = 0.f;
            for (int l2 = 0; l2 < 16; ++l2) {
                float x0 = ludg[2 * l2], x1 = ludg[2 * l2 + 1];
                float dg0 = 0.001f + ((x0 > 15.f) ? x0 : log1pf(expf(x0)));
                float dg1 = 0.001f + ((x1 > 15.f) ? x1 : log1pf(expf(x1)));
                ssum += logf(dg0) + logf(dg1);
            }
            *(float*)(ws + LDC_OFF) = ssum;
        }
    }
}

// ------------- kernel 2: table evaluation (p1 -> knots), wave-private trunk -------------
extern "C" __global__ __launch_bounds__(256, 2)
void nsf_eval(const float* __restrict__ bresg, const float* __restrict__ b0g,
              const float* __restrict__ bfg, char* __restrict__ ws)
{
    __shared__ float R[128 * 68];
    __shared__ float p1sh[64 * 24];
    const int tid = threadIdx.x;
    const int og = tid & 15, pg = tid >> 4;
    const int u0 = og * 8;
    const int L = blockIdx.x >> 5;
    const int pb = (blockIdx.x & 31) << 6;

    const float* WT  = (const float*)(ws + WT_OFF);
    const float* WFT = (const float*)(ws + WFT_OFF);
    const float* ws0 = (const float*)(ws + WS0_OFF);
    const float* bp  = (const float*)(ws + BP_OFF);
    float* tab = (float*)(ws + TAB_OFF);

    float H[8][4];
    {
        float4 s4 = *(const float4*)(bp + L * NPT + pb + pg * 4);
        float sp[4] = {s4.x, s4.y, s4.z, s4.w};
        float4 a0 = *(const float4*)(ws0 + L * 128 + u0);
        float4 a1 = *(const float4*)(ws0 + L * 128 + u0 + 4);
        float4 c0 = *(const float4*)(b0g + L * 128 + u0);
        float4 c1 = *(const float4*)(b0g + L * 128 + u0 + 4);
        float aj[8] = {a0.x, a0.y, a0.z, a0.w, a1.x, a1.y, a1.z, a1.w};
        float cj[8] = {c0.x, c0.y, c0.z, c0.w, c1.x, c1.y, c1.z, c1.w};
#pragma unroll
        for (int j = 0; j < 8; ++j) {
#pragma unroll
            for (int p = 0; p < 4; ++p) H[j][p] = fmaf(aj[j], sp[p], cj[j]);
            float4 v = {fmaxf(H[j][0], 0.f), fmaxf(H[j][1], 0.f),
                        fmaxf(H[j][2], 0.f), fmaxf(H[j][3], 0.f)};
            *(float4*)(&R[(u0 + j) * 68 + pg * 4]) = v;
        }
    }
    __threadfence_block();

#pragma unroll 1
    for (int st = 0; st < 4; ++st) {
        const float* Wst = WT + (L * 4 + st) * 16384;
        const float* bb  = bresg + (L * 4 + st) * 128;
        float acc[8][4];
        {
            float4 b0v = *(const float4*)(bb + u0);
            float4 b1v = *(const float4*)(bb + u0 + 4);
            float bj[8] = {b0v.x, b0v.y, b0v.z, b0v.w, b1v.x, b1v.y, b1v.z, b1v.w};
#pragma unroll
            for (int j = 0; j < 8; ++j)
#pragma unroll
                for (int p = 0; p < 4; ++p) acc[j][p] = bj[j];
        }
#pragma unroll 4
        for (int k = 0; k < 128; ++k) {
            float4 w0 = *(const float4*)(Wst + k * 128 + u0);
            float4 w1 = *(const float4*)(Wst + k * 128 + u0 + 4);
            float4 r  = *(const float4*)(&R[k * 68 + pg * 4]);
            float wj[8] = {w0.x, w0.y, w0.z, w0.w, w1.x, w1.y, w1.z, w1.w};
            float rp[4] = {r.x, r.y, r.z, r.w};
#pragma unroll
            for (int j = 0; j < 8; ++j)
#pragma unroll
                for (int p = 0; p < 4; ++p)
                    acc[j][p] = fmaf(wj[j], rp[p], acc[j][p]);
        }
        if (st == 1 || st == 3) {
#pragma unroll
            for (int j = 0; j < 8; ++j)
#pragma unroll
                for (int p = 0; p < 4; ++p) H[j][p] += acc[j][p];
        }
#pragma unroll
        for (int j = 0; j < 8; ++j) {
            float4 v;
            if (st == 0 || st == 2) {
                v = (float4){fmaxf(acc[j][0], 0.f), fmaxf(acc[j][1], 0.f),
                             fmaxf(acc[j][2], 0.f), fmaxf(acc[j][3], 0.f)};
            } else if (st == 1) {
                v = (float4){fmaxf(H[j][0], 0.f), fmaxf(H[j][1], 0.f),
                             fmaxf(H[j][2], 0.f), fmaxf(H[j][3], 0.f)};
            } else {
                v = (float4){H[j][0], H[j][1], H[j][2], H[j][3]};
            }
            *(float4*)(&R[(u0 + j) * 68 + pg * 4]) = v;
        }
        __threadfence_block();
    }

    // projection -> p1sh (staged for the knot phase)
    {
        const int o = tid & 31, pg8 = tid >> 5;
        float pacc[8];
#pragma unroll
        for (int p = 0; p < 8; ++p) pacc[p] = 0.f;
#pragma unroll 4
        for (int k = 0; k < 128; ++k) {
            float wf = WFT[(L * 128 + k) * 32 + o];
            float4 ra = *(const float4*)(&R[k * 68 + pg8 * 8]);
            float4 rb = *(const float4*)(&R[k * 68 + pg8 * 8 + 4]);
            pacc[0] = fmaf(wf, ra.x, pacc[0]);
            pacc[1] = fmaf(wf, ra.y, pacc[1]);
            pacc[2] = fmaf(wf, ra.z, pacc[2]);
            pacc[3] = fmaf(wf, ra.w, pacc[3]);
            pacc[4] = fmaf(wf, rb.x, pacc[4]);
            pacc[5] = fmaf(wf, rb.y, pacc[5]);
            pacc[6] = fmaf(wf, rb.z, pacc[6]);
            pacc[7] = fmaf(wf, rb.w, pacc[7]);
        }
        if (o < 23) {
            float bias = bfg[L * 46 + 23 + o];
#pragma unroll
            for (int p = 0; p < 8; ++p)
                p1sh[(pg8 * 8 + p) * 24 + o] = pacc[p] + bias;
        }
    }
    __syncthreads();

    // knot phase: one lane per point; store cw1..8 | ch1..8 | d1..7 | bp
    if (tid < 64) {
        float pp[23];
#pragma unroll
        for (int j = 0; j < 23; ++j) pp[j] = p1sh[tid * 24 + j];
        float cw[9], ch[9], d[9];
        knots_from_p(pp, cw, ch, d);
        float out[24];
#pragma unroll
        for (int i = 0; i < 8; ++i) out[i] = cw[i + 1];
#pragma unroll
        for (int i = 0; i < 8; ++i) out[8 + i] = ch[i + 1];
#pragma unroll
        for (int i = 0; i < 7; ++i) out[16 + i] = d[i + 1];
        out[23] = bp[L * NPT + pb + tid];
        float4* dst = (float4*)(tab + (L * NPT + pb + tid) * TROW);
#pragma unroll
        for (int i = 0; i < 6; ++i)
            dst[i] = ((const float4*)out)[i];
    }
}

// ------------- kernel 3: per-sample flow; knot lerp + O(1) grid locate -------------
extern "C" __global__ __launch_bounds__(256)
void nsf_main(const float* __restrict__ z0g, const float* __restrict__ xg,
              const float* __restrict__ sgg,
              const float* __restrict__ n1w1, const float* __restrict__ n1b1,
              const float* __restrict__ n1w2, const float* __restrict__ n1b2,
              const float* __restrict__ n2w1, const float* __restrict__ n2b1,
              const float* __restrict__ n2w2, const float* __restrict__ n2b2,
              const char* __restrict__ ws, float* __restrict__ outg)
{
    __shared__ float xsl[16 * 128];
    __shared__ float recs_s[16 * 40];

    const float* xsg  = (const float*)(ws + XS_OFF);
    const float* tab  = (const float*)(ws + TAB_OFF);
    const float* recg = (const float*)(ws + REC_OFF);

    const int tid = threadIdx.x;
    const int s = blockIdx.x * 256 + tid;

    for (int i = tid; i < 2048; i += 256) xsl[i] = xsg[i];
    for (int i = tid; i < 640; i += 256) recs_s[i] = recg[i];
    __syncthreads();

    float zz0, zz1, ld = 0.f;
    {
        float za = z0g[2 * s], zb = z0g[2 * s + 1];
        float xa = xg[2 * s],  xb = xg[2 * s + 1];
        float sg = sgg[s];
        float t0 = n1b2[0], t1 = n1b2[1];
#pragma unroll
        for (int m = 0; m < 32; ++m) {
            float hm = fmaf(sg, n1w1[m], n1b1[m]);
            hm = hm / (1.f + __expf(-hm));
            t0 = fmaf(hm, n1w2[m], t0);
            t1 = fmaf(hm, n1w2[32 + m], t1);
        }
        float u0 = n2b2[0], u1 = n2b2[1];
#pragma unroll
        for (int m = 0; m < 32; ++m) {
            float hm = za * n2w1[4 * m] + zb * n2w1[4 * m + 1]
                     + xa * n2w1[4 * m + 2] + xb * n2w1[4 * m + 3] + n2b1[m];
            hm = hm / (1.f + __expf(-hm));
            u0 = fmaf(hm, n2w2[m], u0);
            u1 = fmaf(hm, n2w2[32 + m], u1);
        }
        zz0 = u0 + t0; zz1 = u1 + t1;
    }

    for (int L = 0; L < 16; ++L) {
        const float* rec = recs_s + L * 40;
        float out0, ldp0;
        rqs_knots(zz0, rec, out0, ldp0);

        int cg = cnt_grid_le_fast(out0);
        const float* xs = xsl + L * 128;
        int cx = 0;
#pragma unroll
        for (int stp = 64; stp; stp >>= 1)
            if (xs[cx + stp - 1] <= out0) cx += stp;
        int pos = cg + cx - 1;
        pos = max(0, min(pos, NPT - 2));

        const float4* r4 = (const float4*)(tab + (L * NPT + pos) * TROW);
        float f0[24], f1[24];
#pragma unroll
        for (int i = 0; i < 6; ++i) {
            float4 a = r4[i], b = r4[i + 6];
            f0[4 * i] = a.x; f0[4 * i + 1] = a.y; f0[4 * i + 2] = a.z; f0[4 * i + 3] = a.w;
            f1[4 * i] = b.x; f1[4 * i + 1] = b.y; f1[4 * i + 2] = b.z; f1[4 * i + 3] = b.w;
        }
        float e0 = f0[23], e1 = f1[23];
        float de = e1 - e0;
        float tt = (de > 1e-9f) ? (out0 - e0) / de : 0.f;

        float cw[9], ch[9], d[9];
        cw[0] = -3.f; ch[0] = -3.f; d[0] = 1.f; d[8] = 1.f;
#pragma unroll
        for (int i = 0; i < 8; ++i) cw[i + 1] = fmaf(tt, f1[i] - f0[i], f0[i]);
#pragma unroll
        for (int i = 0; i < 8; ++i) ch[i + 1] = fmaf(tt, f1[8 + i] - f0[8 + i], f0[8 + i]);
#pragma unroll
        for (int i = 0; i < 7; ++i) d[i + 1] = fmaf(tt, f1[16 + i] - f0[16 + i], f0[16 + i]);

        float out1, ldp1;
        rqs_from_knots(zz1, cw, ch, d, out1, ldp1);
        ld += ldp0 + ldp1;

        float v0 = out0 - rec[31], v1 = out1 - rec[32];
        zz0 = fmaf(v0, rec[27], v1 * rec[28]);
        zz1 = fmaf(v0, rec[29], v1 * rec[30]);
    }

    float ldc = *(const float*)(ws + LDC_OFF);
    outg[2 * s] = zz0;
    outg[2 * s + 1] = zz1;
    outg[2 * NBATCH + s] = ld - ldc;
}

extern "C" void kernel_launch(void* const* d_in, const int* in_sizes, int n_in,
                              void* d_out, int out_size, void* d_ws, size_t ws_size,
                              hipStream_t stream)
{
    const float* z0g  = (const float*)d_in[0];
    const float* xg   = (const float*)d_in[1];
    const float* sgg  = (const float*)d_in[2];
    const float* n1w1 = (const float*)d_in[3];
    const float* n1b1 = (const float*)d_in[4];
    const float* n1w2 = (const float*)d_in[5];
    const float* n1b2 = (const float*)d_in[6];
    const float* n2w1 = (const float*)d_in[7];
    const float* n2b1 = (const float*)d_in[8];
    const float* n2w2 = (const float*)d_in[9];
    const float* n2b2 = (const float*)d_in[10];
    const float* W0g  = (const float*)d_in[11];
    const float* b0g  = (const float*)d_in[12];
    const float* Wres = (const float*)d_in[13];
    const float* bres = (const float*)d_in[14];
    const float* Wfg  = (const float*)d_in[15];
    const float* bfg  = (const float*)d_in[16];
    const float* lul  = (const float*)d_in[17];
    const float* luu  = (const float*)d_in[18];
    const float* lud  = (const float*)d_in[19];
    const float* lub  = (const float*)d_in[20];
    const int*   perms= (const int*)d_in[21];
    float* outg = (float*)d_out;
    char* ws = (char*)d_ws;

    nsf_prep<<<256, 256, 0, stream>>>(Wres, Wfg, W0g, b0g, bfg, lul, luu, lud, lub, perms, ws);
    nsf_eval<<<512, 256, 0, stream>>>(bres, b0g, bfg, ws);
    nsf_main<<<NBATCH / 256, 256, 0, stream>>>(z0g, xg, sgg,
                                               n1w1, n1b1, n1w2, n1b2,
                                               n2w1, n2b1, n2w2, n2b2,
                                               ws, outg);
}